// Round 9
// baseline (263.719 us; speedup 1.0000x reference)
//
#include <hip/hip_runtime.h>
#include <hip/hip_fp16.h>

#define S_LEN    1024
#define B_SZ     8
#define D_IN     64
#define D_OUT    96
#define NB       8
#define NE       (D_OUT * D_OUT)          // 9216
#define CHUNK    8                        // s-steps per recurrence chain
#define NCHUNK   (S_LEN / CHUNK)          // 128
#define NT_P     256
#define NWBLK    (NCHUNK * (NE / NT_P))   // 4608 W-recurrence blocks
#define GROWS    32                       // (b,s)-rows per GEMM block
#define NROWS    (B_SZ * S_LEN)           // 8192
#define NGBLK    (NROWS / GROWS)          // 256 GEMM blocks
#define WPITCH   104                      // halves; 52 words: 8-lane b128 groups tile all 32 banks
#define NT_C     512                      // 8 waves = 8 batch rows
#define SPAD     100
#define XPAD     68

__device__ __forceinline__ float cos_rev(float v) {   // cos(2*pi*v), v in revolutions
    v -= floorf(v);
    return __builtin_amdgcn_cosf(v);
}

// ---------------- Producer: W1/W2 recurrence + layer-1 GEMMs, one launch ----------------
__global__ void __launch_bounds__(NT_P)
producer(const float* __restrict__ P1, const float* __restrict__ P2,
         const float* __restrict__ seq, const float* __restrict__ M1,
         const float* __restrict__ Wres1,
         __half* __restrict__ W1, __half* __restrict__ W2,
         float* __restrict__ XT, float* __restrict__ RS) {
    const int tid = threadIdx.x;
    if (blockIdx.x < NWBLK) {
        // --- W part: c(s+1) = 2cos(2pi/p)c(s) - c(s-1) ---
        const int c  = blockIdx.x / (NE / NT_P);
        const int eb = blockIdx.x % (NE / NT_P);
        const int e  = eb * NT_P + tid;
        const int s0 = c * CHUNK;
        const float s0f = (float)s0;

        float p1l[NB], p2l[NB];
        *(float4*)&p1l[0] = *(const float4*)(P1 + e * NB);
        *(float4*)&p1l[4] = *(const float4*)(P1 + e * NB + 4);
        *(float4*)&p2l[0] = *(const float4*)(P2 + e * NB);
        *(float4*)&p2l[4] = *(const float4*)(P2 + e * NB + 4);

        float cc[NB], cp[NB], kk[NB];
        #pragma unroll
        for (int g = 0; g < NB; ++g) {
            const float inv = __builtin_amdgcn_rcpf((float)(e * NB + 2 + g));
            cc[g] = cos_rev(s0f * inv);
            cp[g] = cos_rev((s0f - 1.0f) * inv);
            kk[g] = 2.0f * __builtin_amdgcn_cosf(inv);   // inv <= 0.5 rev
        }
        #pragma unroll
        for (int s = s0; s < s0 + CHUNK; ++s) {
            float a1 = 0.0f, a2 = 0.0f;
            #pragma unroll
            for (int g = 0; g < NB; ++g) {
                a1 = fmaf(p1l[g], cc[g], a1);
                a2 = fmaf(p2l[g], cc[g], a2);
            }
            W1[s * NE + e] = __float2half(a1);
            W2[s * NE + e] = __float2half(a2);
            #pragma unroll
            for (int g = 0; g < NB; ++g) {
                float cn = fmaf(kk[g], cc[g], -cp[g]);
                cp[g] = cc[g];
                cc[g] = cn;
            }
        }
    } else {
        // --- layer-1 GEMM part: xt1 = seq@M1^T, res1 = seq@Wres1^T ---
        __shared__ __align__(16) float xs[GROWS * XPAD];
        const int r0 = (blockIdx.x - NWBLK) * GROWS;
        for (int cdx = tid; cdx < GROWS * (D_IN / 4); cdx += NT_P) {
            int rr = cdx >> 4, q = cdx & 15;
            *(float4*)(xs + rr * XPAD + q * 4) =
                *(const float4*)(seq + (size_t)(r0 + rr) * D_IN + q * 4);
        }
        __syncthreads();
        const int rr = tid >> 3;     // 0..31 row within tile
        const int ig = tid & 7;      // i-group
        const float* xr = xs + rr * XPAD;
        #pragma unroll
        for (int ii = 0; ii < 12; ++ii) {
            const int i = ig + ii * 8;          // 8 lanes share each M row
            const float4* m = (const float4*)(M1 + i * D_IN);
            const float4* w = (const float4*)(Wres1 + i * D_IN);
            float at = 0.0f, ar = 0.0f;
            #pragma unroll
            for (int k = 0; k < D_IN / 4; ++k) {
                float4 mv = m[k], rv = w[k];
                float4 xv = *(const float4*)(xr + 4 * k);
                at = fmaf(mv.x, xv.x, fmaf(mv.y, xv.y, fmaf(mv.z, xv.z, fmaf(mv.w, xv.w, at))));
                ar = fmaf(rv.x, xv.x, fmaf(rv.y, xv.y, fmaf(rv.z, xv.z, fmaf(rv.w, xv.w, ar))));
            }
            XT[(size_t)(r0 + rr) * D_OUT + i] = at;
            RS[(size_t)(r0 + rr) * D_OUT + i] = ar;
        }
    }
}

// ---------------- consumer helpers ----------------
__device__ __forceinline__ float nkdot(const __half* __restrict__ wrow,
                                       const float* __restrict__ xr) {
    float acc = 0.0f;
    #pragma unroll
    for (int j = 0; j < 12; ++j) {
        float4 raw = *(const float4*)(wrow + 8 * j);
        const __half2* hp = (const __half2*)&raw;
        float2 c0 = __half22float2(hp[0]);
        float2 c1 = __half22float2(hp[1]);
        float2 c2 = __half22float2(hp[2]);
        float2 c3 = __half22float2(hp[3]);
        float4 x0 = *(const float4*)(xr + 8 * j);
        float4 x1 = *(const float4*)(xr + 8 * j + 4);
        acc = fmaf(c0.x, x0.x, acc); acc = fmaf(c0.y, x0.y, acc);
        acc = fmaf(c1.x, x0.z, acc); acc = fmaf(c1.y, x0.w, acc);
        acc = fmaf(c2.x, x1.x, acc); acc = fmaf(c2.y, x1.y, acc);
        acc = fmaf(c3.x, x1.z, acc); acc = fmaf(c3.y, x1.w, acc);
    }
    return acc;
}

__device__ __forceinline__ float gemv96(const float* __restrict__ mrow,
                                        const float* __restrict__ xr) {
    float acc = 0.0f;
    #pragma unroll
    for (int k = 0; k < 24; ++k) {
        float4 mv = *(const float4*)(mrow + 4 * k);
        float4 xv = *(const float4*)(xr + 4 * k);
        acc = fmaf(mv.x, xv.x, fmaf(mv.y, xv.y, fmaf(mv.z, xv.z, fmaf(mv.w, xv.w, acc))));
    }
    return acc;
}

// ---------------- Consumer: single W buffer staged twice, wave-per-row ----------------
// LDS 23168 B -> wave-limit binds: 4 blocks/CU x 1024 blocks = exactly 4/CU, no tail.
__global__ void __launch_bounds__(NT_C, 4)
consumer(const float* __restrict__ XT, const float* __restrict__ RS,
         const float* __restrict__ M2,
         const float* __restrict__ g1, const float* __restrict__ b1,
         const float* __restrict__ g2, const float* __restrict__ b2,
         const __half* __restrict__ W1g, const __half* __restrict__ W2g,
         float* __restrict__ out) {
    __shared__ __align__(16) __half wh  [D_OUT * WPITCH];   // 19968 B, reused for W1 then W2
    __shared__ __align__(16) float  xbuf[B_SZ * SPAD];      //  3200 B

    const int s    = blockIdx.x;
    const int tid  = threadIdx.x;
    const int b    = tid >> 6;
    const int lane = tid & 63;
    const bool lo  = (lane < 32);

    // stage W1[s]
    {
        const __half* W1s = W1g + (size_t)s * NE;
        for (int c = tid; c < NE / 8; c += NT_C) {
            int i = c / 12, j = (c % 12) * 8;
            *(float4*)(wh + i * WPITCH + j) = *(const float4*)(W1s + c * 8);
        }
    }
    // per-wave inputs: lane l owns features {l, 64+l(<96)} — coalesced
    const size_t r = (size_t)b * S_LEN + s;
    float xt0 = XT[r * D_OUT + lane];
    float rs0 = RS[r * D_OUT + lane];
    float xt1 = 0.0f, rs1 = 0.0f;
    if (lo) {
        xt1 = XT[r * D_OUT + 64 + lane];
        rs1 = RS[r * D_OUT + 64 + lane];
    }
    __syncthreads();   // B1

    float* xr = xbuf + b * SPAD;   // wave-private row: LDS w->r ordered in-wave

    // ---- LN1 (in-wave) ----
    {
        float sum = xt0 + xt1;
        float sq  = fmaf(xt0, xt0, xt1 * xt1);
        #pragma unroll
        for (int off = 32; off > 0; off >>= 1) {
            sum += __shfl_down(sum, off, 64);
            sq  += __shfl_down(sq,  off, 64);
        }
        sum = __shfl(sum, 0, 64);
        sq  = __shfl(sq,  0, 64);
        const float mu  = sum * (1.0f / 96.0f);
        const float var = fmaf(sq, 1.0f / 96.0f, -(mu * mu));
        const float rst = rsqrtf(var + 1e-5f);
        xr[lane] = fmaf((xt0 - mu) * rst, g1[lane], b1[lane]);
        if (lo) xr[64 + lane] = fmaf((xt1 - mu) * rst, g1[64 + lane], b1[64 + lane]);
    }

    // ---- Nk1 + residual ----
    float x10 = rs0 + nkdot(wh + lane * WPITCH, xr);
    float x11 = 0.0f;
    if (lo) x11 = rs1 + nkdot(wh + (64 + lane) * WPITCH, xr);
    __syncthreads();   // B2: all waves done reading W1 from wh

    // publish x1 (wave-private row), then restage wh <- W2[s]
    xr[lane] = x10;
    if (lo) xr[64 + lane] = x11;
    {
        const __half* W2s = W2g + (size_t)s * NE;
        for (int c = tid; c < NE / 8; c += NT_C) {
            int i = c / 12, j = (c % 12) * 8;
            *(float4*)(wh + i * WPITCH + j) = *(const float4*)(W2s + c * 8);
        }
    }
    // layer-2 GEMV overlaps the W2 staging drain (doesn't touch wh)
    float t0 = gemv96(M2 + lane * D_OUT, xr);
    float t1 = 0.0f;
    if (lo) t1 = gemv96(M2 + (64 + lane) * D_OUT, xr);
    __syncthreads();   // B3: wh holds W2

    // ---- LN2 ----
    {
        float sum = t0 + t1;
        float sq  = fmaf(t0, t0, t1 * t1);
        #pragma unroll
        for (int off = 32; off > 0; off >>= 1) {
            sum += __shfl_down(sum, off, 64);
            sq  += __shfl_down(sq,  off, 64);
        }
        sum = __shfl(sum, 0, 64);
        sq  = __shfl(sq,  0, 64);
        const float mu  = sum * (1.0f / 96.0f);
        const float var = fmaf(sq, 1.0f / 96.0f, -(mu * mu));
        const float rst = rsqrtf(var + 1e-5f);
        xr[lane] = fmaf((t0 - mu) * rst, g2[lane], b2[lane]);
        if (lo) xr[64 + lane] = fmaf((t1 - mu) * rst, g2[64 + lane], b2[64 + lane]);
    }

    // ---- Nk2 + identity residual -> out (coalesced) ----
    out[r * D_OUT + lane] = nkdot(wh + lane * WPITCH, xr) + x10;
    if (lo)
        out[r * D_OUT + 64 + lane] = nkdot(wh + (64 + lane) * WPITCH, xr) + x11;
}

// ---------------- Fallback (round-1 proven kernel) if ws too small ----------------
__global__ void __launch_bounds__(NT_P)
hier_fallback(const float* __restrict__ seq,  const float* __restrict__ M1,
              const float* __restrict__ P1,   const float* __restrict__ Wres1,
              const float* __restrict__ g1,   const float* __restrict__ b1,
              const float* __restrict__ M2,   const float* __restrict__ P2,
              const float* __restrict__ g2,   const float* __restrict__ b2,
              float* __restrict__ out) {
    __shared__ __align__(16) float w[D_OUT * SPAD];
    __shared__ __align__(16) float xin[B_SZ * XPAD];
    __shared__ __align__(16) float xn [B_SZ * SPAD];
    __shared__ __align__(16) float x1b[B_SZ * SPAD];
    const int s = blockIdx.x, tid = threadIdx.x;
    const float sf = (float)s;

    for (int idx = tid; idx < B_SZ * D_IN; idx += NT_P) {
        int b = idx >> 6, k = idx & (D_IN - 1);
        xin[b * XPAD + k] = seq[(b * S_LEN + s) * D_IN + k];
    }
    for (int e = tid; e < NE; e += NT_P) {
        float pl[8];
        *(float4*)&pl[0] = *(const float4*)(P1 + e * NB);
        *(float4*)&pl[4] = *(const float4*)(P1 + e * NB + 4);
        float acc = 0.0f;
        #pragma unroll
        for (int g = 0; g < NB; ++g) {
            float v = sf * __builtin_amdgcn_rcpf((float)(e * NB + 2 + g));
            acc = fmaf(pl[g], cos_rev(v), acc);
        }
        int i = e / D_OUT;
        w[e + (SPAD - D_OUT) * i] = acc;
    }
    __syncthreads();
    for (int idx = tid; idx < B_SZ * D_OUT; idx += NT_P) {
        int i = idx >> 3, b = idx & 7;
        const float4* m  = (const float4*)(M1 + i * D_IN);
        const float4* wr = (const float4*)(Wres1 + i * D_IN);
        const float*  xr = xin + b * XPAD;
        float at = 0.0f, ar = 0.0f;
        #pragma unroll
        for (int k = 0; k < D_IN / 4; ++k) {
            float4 mv = m[k], rv = wr[k];
            float x0 = xr[4*k], x1 = xr[4*k+1], x2 = xr[4*k+2], x3 = xr[4*k+3];
            at = fmaf(mv.x, x0, fmaf(mv.y, x1, fmaf(mv.z, x2, fmaf(mv.w, x3, at))));
            ar = fmaf(rv.x, x0, fmaf(rv.y, x1, fmaf(rv.z, x2, fmaf(rv.w, x3, ar))));
        }
        xn [b * SPAD + i] = at;
        x1b[b * SPAD + i] = ar;
    }
    __syncthreads();
    {
        const int b = tid >> 5, rr = tid & 31;
        float* row = xn + b * SPAD;
        float v0 = row[rr], v1 = row[rr + 32], v2 = row[rr + 64];
        float sum = v0 + v1 + v2, sq = fmaf(v0, v0, fmaf(v1, v1, v2 * v2));
        #pragma unroll
        for (int off = 16; off > 0; off >>= 1) {
            sum += __shfl_down(sum, off, 32);
            sq  += __shfl_down(sq,  off, 32);
        }
        sum = __shfl(sum, 0, 32); sq = __shfl(sq, 0, 32);
        float mu = sum * (1.0f/96.0f), var = fmaf(sq, 1.0f/96.0f, -(mu*mu));
        float rs = rsqrtf(var + 1e-5f);
        row[rr]      = fmaf((v0 - mu) * rs, g1[rr],      b1[rr]);
        row[rr + 32] = fmaf((v1 - mu) * rs, g1[rr + 32], b1[rr + 32]);
        row[rr + 64] = fmaf((v2 - mu) * rs, g1[rr + 64], b1[rr + 64]);
    }
    __syncthreads();
    for (int idx = tid; idx < B_SZ * D_OUT; idx += NT_P) {
        int i = idx >> 3, b = idx & 7;
        const float* wrow = w + i * SPAD;
        const float* xr   = xn + b * SPAD;
        float acc = 0.0f;
        #pragma unroll
        for (int j = 0; j < D_OUT / 4; ++j) {
            float4 wv = *(const float4*)(wrow + 4 * j);
            float4 xv = *(const float4*)(xr + 4 * j);
            acc = fmaf(wv.x, xv.x, fmaf(wv.y, xv.y, fmaf(wv.z, xv.z, fmaf(wv.w, xv.w, acc))));
        }
        x1b[b * SPAD + i] += acc;
    }
    __syncthreads();
    for (int e = tid; e < NE; e += NT_P) {
        float pl[8];
        *(float4*)&pl[0] = *(const float4*)(P2 + e * NB);
        *(float4*)&pl[4] = *(const float4*)(P2 + e * NB + 4);
        float acc = 0.0f;
        #pragma unroll
        for (int g = 0; g < NB; ++g) {
            float v = sf * __builtin_amdgcn_rcpf((float)(e * NB + 2 + g));
            acc = fmaf(pl[g], cos_rev(v), acc);
        }
        int i = e / D_OUT;
        w[e + (SPAD - D_OUT) * i] = acc;
    }
    for (int idx = tid; idx < B_SZ * D_OUT; idx += NT_P) {
        int i = idx >> 3, b = idx & 7;
        const float4* m  = (const float4*)(M2 + i * D_OUT);
        const float*  xr = x1b + b * SPAD;
        float at = 0.0f;
        #pragma unroll
        for (int k = 0; k < D_OUT / 4; ++k) {
            float4 mv = m[k];
            at = fmaf(mv.x, xr[4*k], fmaf(mv.y, xr[4*k+1],
                 fmaf(mv.z, xr[4*k+2], fmaf(mv.w, xr[4*k+3], at))));
        }
        xn[b * SPAD + i] = at;
    }
    __syncthreads();
    {
        const int b = tid >> 5, rr = tid & 31;
        float* row = xn + b * SPAD;
        float v0 = row[rr], v1 = row[rr + 32], v2 = row[rr + 64];
        float sum = v0 + v1 + v2, sq = fmaf(v0, v0, fmaf(v1, v1, v2 * v2));
        #pragma unroll
        for (int off = 16; off > 0; off >>= 1) {
            sum += __shfl_down(sum, off, 32);
            sq  += __shfl_down(sq,  off, 32);
        }
        sum = __shfl(sum, 0, 32); sq = __shfl(sq, 0, 32);
        float mu = sum * (1.0f/96.0f), var = fmaf(sq, 1.0f/96.0f, -(mu*mu));
        float rs = rsqrtf(var + 1e-5f);
        row[rr]      = fmaf((v0 - mu) * rs, g2[rr],      b2[rr]);
        row[rr + 32] = fmaf((v1 - mu) * rs, g2[rr + 32], b2[rr + 32]);
        row[rr + 64] = fmaf((v2 - mu) * rs, g2[rr + 64], b2[rr + 64]);
    }
    __syncthreads();
    for (int idx = tid; idx < B_SZ * D_OUT; idx += NT_P) {
        int i = idx >> 3, b = idx & 7;
        const float* wrow = w + i * SPAD;
        const float* xr   = xn + b * SPAD;
        float acc = 0.0f;
        #pragma unroll
        for (int j = 0; j < D_OUT / 4; ++j) {
            float4 wv = *(const float4*)(wrow + 4 * j);
            float4 xv = *(const float4*)(xr + 4 * j);
            acc = fmaf(wv.x, xv.x, fmaf(wv.y, xv.y, fmaf(wv.z, xv.z, fmaf(wv.w, xv.w, acc))));
        }
        out[(b * S_LEN + s) * D_OUT + i] = acc + x1b[b * SPAD + i];
    }
}

extern "C" void kernel_launch(void* const* d_in, const int* in_sizes, int n_in,
                              void* d_out, int out_size, void* d_ws, size_t ws_size,
                              hipStream_t stream) {
    const float* seq   = (const float*)d_in[0];
    const float* M1    = (const float*)d_in[1];
    const float* P1    = (const float*)d_in[2];
    const float* Wres1 = (const float*)d_in[3];
    const float* g1    = (const float*)d_in[4];
    const float* b1    = (const float*)d_in[5];
    const float* M2    = (const float*)d_in[6];
    const float* P2    = (const float*)d_in[7];
    const float* g2    = (const float*)d_in[8];
    const float* b2    = (const float*)d_in[9];
    float* out = (float*)d_out;

    const size_t w_bytes  = (size_t)2 * S_LEN * NE * sizeof(__half);      // 37.75 MB
    const size_t xt_bytes = (size_t)NROWS * D_OUT * sizeof(float);        // 3.15 MB
    const size_t need     = w_bytes + 2 * xt_bytes;
    if (ws_size >= need) {
        __half* W1 = (__half*)d_ws;
        __half* W2 = W1 + (size_t)S_LEN * NE;
        float*  XT = (float*)((char*)d_ws + w_bytes);
        float*  RS = XT + (size_t)NROWS * D_OUT;
        producer<<<dim3(NWBLK + NGBLK), dim3(NT_P), 0, stream>>>(
            P1, P2, seq, M1, Wres1, W1, W2, XT, RS);
        consumer<<<dim3(S_LEN), dim3(NT_C), 0, stream>>>(
            XT, RS, M2, g1, b1, g2, b2, W1, W2, out);
    } else {
        hier_fallback<<<dim3(S_LEN), dim3(NT_P), 0, stream>>>(
            seq, M1, P1, Wres1, g1, b1, M2, P2, g2, b2, out);
    }
}

// Round 10
// 193.865 us; speedup vs baseline: 1.3603x; 1.3603x over previous
//
#include <hip/hip_runtime.h>
#include <hip/hip_fp16.h>

#define S_LEN    1024
#define B_SZ     8
#define D_IN     64
#define D_OUT    96
#define NB       8
#define NE       (D_OUT * D_OUT)          // 9216
#define CHUNK    8                        // s-steps per recurrence chain
#define NCHUNK   (S_LEN / CHUNK)          // 128
#define NT_P     256
#define NWBLK    (NCHUNK * (NE / NT_P))   // 4608 W-recurrence blocks
#define GROWS    32                       // (b,s)-rows per GEMM block
#define NROWS    (B_SZ * S_LEN)           // 8192
#define NGBLK    (NROWS / GROWS)          // 256 GEMM blocks
#define WPITCH   104                      // halves; 52 words: 8-lane b128 groups tile all 32 banks
#define NT_C     512                      // 8 waves = 8 batch rows
#define SPAD     100
#define XPAD     68

__device__ __forceinline__ float cos_rev(float v) {   // cos(2*pi*v), v in revolutions
    v -= floorf(v);
    return __builtin_amdgcn_cosf(v);
}

// ---------------- Producer: W1/W2 recurrence + layer-1 GEMMs, one launch ----------------
__global__ void __launch_bounds__(NT_P)
producer(const float* __restrict__ P1, const float* __restrict__ P2,
         const float* __restrict__ seq, const float* __restrict__ M1,
         const float* __restrict__ Wres1,
         __half* __restrict__ W1, __half* __restrict__ W2,
         float* __restrict__ XT, float* __restrict__ RS) {
    const int tid = threadIdx.x;
    if (blockIdx.x < NWBLK) {
        // --- W part: c(s+1) = 2cos(2pi/p)c(s) - c(s-1) ---
        const int c  = blockIdx.x / (NE / NT_P);
        const int eb = blockIdx.x % (NE / NT_P);
        const int e  = eb * NT_P + tid;
        const int s0 = c * CHUNK;
        const float s0f = (float)s0;

        float p1l[NB], p2l[NB];
        *(float4*)&p1l[0] = *(const float4*)(P1 + e * NB);
        *(float4*)&p1l[4] = *(const float4*)(P1 + e * NB + 4);
        *(float4*)&p2l[0] = *(const float4*)(P2 + e * NB);
        *(float4*)&p2l[4] = *(const float4*)(P2 + e * NB + 4);

        float cc[NB], cp[NB], kk[NB];
        #pragma unroll
        for (int g = 0; g < NB; ++g) {
            const float inv = __builtin_amdgcn_rcpf((float)(e * NB + 2 + g));
            cc[g] = cos_rev(s0f * inv);
            cp[g] = cos_rev((s0f - 1.0f) * inv);
            kk[g] = 2.0f * __builtin_amdgcn_cosf(inv);   // inv <= 0.5 rev
        }
        #pragma unroll
        for (int s = s0; s < s0 + CHUNK; ++s) {
            float a1 = 0.0f, a2 = 0.0f;
            #pragma unroll
            for (int g = 0; g < NB; ++g) {
                a1 = fmaf(p1l[g], cc[g], a1);
                a2 = fmaf(p2l[g], cc[g], a2);
            }
            W1[s * NE + e] = __float2half(a1);
            W2[s * NE + e] = __float2half(a2);
            #pragma unroll
            for (int g = 0; g < NB; ++g) {
                float cn = fmaf(kk[g], cc[g], -cp[g]);
                cp[g] = cc[g];
                cc[g] = cn;
            }
        }
    } else {
        // --- layer-1 GEMM part: xt1 = seq@M1^T, res1 = seq@Wres1^T ---
        __shared__ __align__(16) float xs[GROWS * XPAD];
        const int r0 = (blockIdx.x - NWBLK) * GROWS;
        for (int cdx = tid; cdx < GROWS * (D_IN / 4); cdx += NT_P) {
            int rr = cdx >> 4, q = cdx & 15;
            *(float4*)(xs + rr * XPAD + q * 4) =
                *(const float4*)(seq + (size_t)(r0 + rr) * D_IN + q * 4);
        }
        __syncthreads();
        const int rr = tid >> 3;     // 0..31 row within tile
        const int ig = tid & 7;      // i-group
        const float* xr = xs + rr * XPAD;
        #pragma unroll
        for (int ii = 0; ii < 12; ++ii) {
            const int i = ig + ii * 8;          // 8 lanes share each M row
            const float4* m = (const float4*)(M1 + i * D_IN);
            const float4* w = (const float4*)(Wres1 + i * D_IN);
            float at = 0.0f, ar = 0.0f;
            #pragma unroll
            for (int k = 0; k < D_IN / 4; ++k) {
                float4 mv = m[k], rv = w[k];
                float4 xv = *(const float4*)(xr + 4 * k);
                at = fmaf(mv.x, xv.x, fmaf(mv.y, xv.y, fmaf(mv.z, xv.z, fmaf(mv.w, xv.w, at))));
                ar = fmaf(rv.x, xv.x, fmaf(rv.y, xv.y, fmaf(rv.z, xv.z, fmaf(rv.w, xv.w, ar))));
            }
            XT[(size_t)(r0 + rr) * D_OUT + i] = at;
            RS[(size_t)(r0 + rr) * D_OUT + i] = ar;
        }
    }
}

// ---------------- consumer helpers ----------------
// Split into two 6-chunk halves (r6-proven) to bound in-flight LDS-load regs.
__device__ __forceinline__ float nkdot(const __half* __restrict__ wrow,
                                       const float* __restrict__ xr) {
    float acc = 0.0f;
    #pragma unroll
    for (int h = 0; h < 2; ++h) {
        #pragma unroll
        for (int j = h * 6; j < h * 6 + 6; ++j) {
            float4 raw = *(const float4*)(wrow + 8 * j);
            const __half2* hp = (const __half2*)&raw;
            float2 c0 = __half22float2(hp[0]);
            float2 c1 = __half22float2(hp[1]);
            float2 c2 = __half22float2(hp[2]);
            float2 c3 = __half22float2(hp[3]);
            float4 x0 = *(const float4*)(xr + 8 * j);
            float4 x1 = *(const float4*)(xr + 8 * j + 4);
            acc = fmaf(c0.x, x0.x, acc); acc = fmaf(c0.y, x0.y, acc);
            acc = fmaf(c1.x, x0.z, acc); acc = fmaf(c1.y, x0.w, acc);
            acc = fmaf(c2.x, x1.x, acc); acc = fmaf(c2.y, x1.y, acc);
            acc = fmaf(c3.x, x1.z, acc); acc = fmaf(c3.y, x1.w, acc);
        }
    }
    return acc;
}

// Global-M2 dot. unroll 4 ONLY: full unroll made the compiler hoist all 24
// float4 global loads -> ~100+ live VGPRs -> spill (r8/r9 FETCH 180+/WRITE 300+ MB).
__device__ float gemv96(const float* __restrict__ mrow,
                        const float* __restrict__ xr) {
    float acc = 0.0f;
    #pragma unroll 4
    for (int k = 0; k < 24; ++k) {
        float4 mv = *(const float4*)(mrow + 4 * k);
        float4 xv = *(const float4*)(xr + 4 * k);
        acc = fmaf(mv.x, xv.x, fmaf(mv.y, xv.y, fmaf(mv.z, xv.z, fmaf(mv.w, xv.w, acc))));
    }
    return acc;
}

// ---------------- Consumer: single W buffer staged twice, wave-per-row ----------------
// NO min-waves clause: (512,N) has twice produced destructive VGPR caps (r5: 32, r9: 64).
__global__ void __launch_bounds__(NT_C)
consumer(const float* __restrict__ XT, const float* __restrict__ RS,
         const float* __restrict__ M2,
         const float* __restrict__ g1, const float* __restrict__ b1,
         const float* __restrict__ g2, const float* __restrict__ b2,
         const __half* __restrict__ W1g, const __half* __restrict__ W2g,
         float* __restrict__ out) {
    __shared__ __align__(16) __half wh  [D_OUT * WPITCH];   // 19968 B, W1 then W2
    __shared__ __align__(16) float  xbuf[B_SZ * SPAD];      //  3200 B

    const int s    = blockIdx.x;
    const int tid  = threadIdx.x;
    const int b    = tid >> 6;
    const int lane = tid & 63;
    const bool lo  = (lane < 32);

    // stage W1[s]
    {
        const __half* W1s = W1g + (size_t)s * NE;
        for (int c = tid; c < NE / 8; c += NT_C) {
            int i = c / 12, j = (c % 12) * 8;
            *(float4*)(wh + i * WPITCH + j) = *(const float4*)(W1s + c * 8);
        }
    }
    // per-wave inputs: lane l owns features {l, 64+l(<96)} — coalesced
    const size_t r = (size_t)b * S_LEN + s;
    float xt0 = XT[r * D_OUT + lane];
    float rs0 = RS[r * D_OUT + lane];
    float xt1 = 0.0f, rs1 = 0.0f;
    if (lo) {
        xt1 = XT[r * D_OUT + 64 + lane];
        rs1 = RS[r * D_OUT + 64 + lane];
    }
    __syncthreads();   // B1

    float* xr = xbuf + b * SPAD;   // wave-private row: LDS w->r ordered in-wave

    // ---- LN1 (in-wave) ----
    {
        float sum = xt0 + xt1;
        float sq  = fmaf(xt0, xt0, xt1 * xt1);
        #pragma unroll
        for (int off = 32; off > 0; off >>= 1) {
            sum += __shfl_down(sum, off, 64);
            sq  += __shfl_down(sq,  off, 64);
        }
        sum = __shfl(sum, 0, 64);
        sq  = __shfl(sq,  0, 64);
        const float mu  = sum * (1.0f / 96.0f);
        const float var = fmaf(sq, 1.0f / 96.0f, -(mu * mu));
        const float rst = rsqrtf(var + 1e-5f);
        xr[lane] = fmaf((xt0 - mu) * rst, g1[lane], b1[lane]);
        if (lo) xr[64 + lane] = fmaf((xt1 - mu) * rst, g1[64 + lane], b1[64 + lane]);
    }

    // ---- Nk1 + residual ----
    float x10 = rs0 + nkdot(wh + lane * WPITCH, xr);
    float x11 = 0.0f;
    if (lo) x11 = rs1 + nkdot(wh + (64 + lane) * WPITCH, xr);
    __syncthreads();   // B2: all waves done reading W1 from wh

    // publish x1 (wave-private row), then restage wh <- W2[s]
    xr[lane] = x10;
    if (lo) xr[64 + lane] = x11;
    {
        const __half* W2s = W2g + (size_t)s * NE;
        for (int c = tid; c < NE / 8; c += NT_C) {
            int i = c / 12, j = (c % 12) * 8;
            *(float4*)(wh + i * WPITCH + j) = *(const float4*)(W2s + c * 8);
        }
    }
    // layer-2 GEMV overlaps the W2 staging drain (doesn't touch wh)
    float t0 = gemv96(M2 + lane * D_OUT, xr);
    float t1 = 0.0f;
    if (lo) t1 = gemv96(M2 + (64 + lane) * D_OUT, xr);
    __syncthreads();   // B3: wh holds W2

    // ---- LN2 ----
    {
        float sum = t0 + t1;
        float sq  = fmaf(t0, t0, t1 * t1);
        #pragma unroll
        for (int off = 32; off > 0; off >>= 1) {
            sum += __shfl_down(sum, off, 64);
            sq  += __shfl_down(sq,  off, 64);
        }
        sum = __shfl(sum, 0, 64);
        sq  = __shfl(sq,  0, 64);
        const float mu  = sum * (1.0f / 96.0f);
        const float var = fmaf(sq, 1.0f / 96.0f, -(mu * mu));
        const float rst = rsqrtf(var + 1e-5f);
        xr[lane] = fmaf((t0 - mu) * rst, g2[lane], b2[lane]);
        if (lo) xr[64 + lane] = fmaf((t1 - mu) * rst, g2[64 + lane], b2[64 + lane]);
    }

    // ---- Nk2 + identity residual -> out (coalesced) ----
    out[r * D_OUT + lane] = nkdot(wh + lane * WPITCH, xr) + x10;
    if (lo)
        out[r * D_OUT + 64 + lane] = nkdot(wh + (64 + lane) * WPITCH, xr) + x11;
}

// ---------------- Fallback (round-1 proven kernel) if ws too small ----------------
__global__ void __launch_bounds__(NT_P)
hier_fallback(const float* __restrict__ seq,  const float* __restrict__ M1,
              const float* __restrict__ P1,   const float* __restrict__ Wres1,
              const float* __restrict__ g1,   const float* __restrict__ b1,
              const float* __restrict__ M2,   const float* __restrict__ P2,
              const float* __restrict__ g2,   const float* __restrict__ b2,
              float* __restrict__ out) {
    __shared__ __align__(16) float w[D_OUT * SPAD];
    __shared__ __align__(16) float xin[B_SZ * XPAD];
    __shared__ __align__(16) float xn [B_SZ * SPAD];
    __shared__ __align__(16) float x1b[B_SZ * SPAD];
    const int s = blockIdx.x, tid = threadIdx.x;
    const float sf = (float)s;

    for (int idx = tid; idx < B_SZ * D_IN; idx += NT_P) {
        int b = idx >> 6, k = idx & (D_IN - 1);
        xin[b * XPAD + k] = seq[(b * S_LEN + s) * D_IN + k];
    }
    for (int e = tid; e < NE; e += NT_P) {
        float pl[8];
        *(float4*)&pl[0] = *(const float4*)(P1 + e * NB);
        *(float4*)&pl[4] = *(const float4*)(P1 + e * NB + 4);
        float acc = 0.0f;
        #pragma unroll
        for (int g = 0; g < NB; ++g) {
            float v = sf * __builtin_amdgcn_rcpf((float)(e * NB + 2 + g));
            acc = fmaf(pl[g], cos_rev(v), acc);
        }
        int i = e / D_OUT;
        w[e + (SPAD - D_OUT) * i] = acc;
    }
    __syncthreads();
    for (int idx = tid; idx < B_SZ * D_OUT; idx += NT_P) {
        int i = idx >> 3, b = idx & 7;
        const float4* m  = (const float4*)(M1 + i * D_IN);
        const float4* wr = (const float4*)(Wres1 + i * D_IN);
        const float*  xr = xin + b * XPAD;
        float at = 0.0f, ar = 0.0f;
        #pragma unroll
        for (int k = 0; k < D_IN / 4; ++k) {
            float4 mv = m[k], rv = wr[k];
            float x0 = xr[4*k], x1 = xr[4*k+1], x2 = xr[4*k+2], x3 = xr[4*k+3];
            at = fmaf(mv.x, x0, fmaf(mv.y, x1, fmaf(mv.z, x2, fmaf(mv.w, x3, at))));
            ar = fmaf(rv.x, x0, fmaf(rv.y, x1, fmaf(rv.z, x2, fmaf(rv.w, x3, ar))));
        }
        xn [b * SPAD + i] = at;
        x1b[b * SPAD + i] = ar;
    }
    __syncthreads();
    {
        const int b = tid >> 5, rr = tid & 31;
        float* row = xn + b * SPAD;
        float v0 = row[rr], v1 = row[rr + 32], v2 = row[rr + 64];
        float sum = v0 + v1 + v2, sq = fmaf(v0, v0, fmaf(v1, v1, v2 * v2));
        #pragma unroll
        for (int off = 16; off > 0; off >>= 1) {
            sum += __shfl_down(sum, off, 32);
            sq  += __shfl_down(sq,  off, 32);
        }
        sum = __shfl(sum, 0, 32); sq = __shfl(sq, 0, 32);
        float mu = sum * (1.0f/96.0f), var = fmaf(sq, 1.0f/96.0f, -(mu*mu));
        float rs = rsqrtf(var + 1e-5f);
        row[rr]      = fmaf((v0 - mu) * rs, g1[rr],      b1[rr]);
        row[rr + 32] = fmaf((v1 - mu) * rs, g1[rr + 32], b1[rr + 32]);
        row[rr + 64] = fmaf((v2 - mu) * rs, g1[rr + 64], b1[rr + 64]);
    }
    __syncthreads();
    for (int idx = tid; idx < B_SZ * D_OUT; idx += NT_P) {
        int i = idx >> 3, b = idx & 7;
        const float* wrow = w + i * SPAD;
        const float* xr   = xn + b * SPAD;
        float acc = 0.0f;
        #pragma unroll
        for (int j = 0; j < D_OUT / 4; ++j) {
            float4 wv = *(const float4*)(wrow + 4 * j);
            float4 xv = *(const float4*)(xr + 4 * j);
            acc = fmaf(wv.x, xv.x, fmaf(wv.y, xv.y, fmaf(wv.z, xv.z, fmaf(wv.w, xv.w, acc))));
        }
        x1b[b * SPAD + i] += acc;
    }
    __syncthreads();
    for (int e = tid; e < NE; e += NT_P) {
        float pl[8];
        *(float4*)&pl[0] = *(const float4*)(P2 + e * NB);
        *(float4*)&pl[4] = *(const float4*)(P2 + e * NB + 4);
        float acc = 0.0f;
        #pragma unroll
        for (int g = 0; g < NB; ++g) {
            float v = sf * __builtin_amdgcn_rcpf((float)(e * NB + 2 + g));
            acc = fmaf(pl[g], cos_rev(v), acc);
        }
        int i = e / D_OUT;
        w[e + (SPAD - D_OUT) * i] = acc;
    }
    for (int idx = tid; idx < B_SZ * D_OUT; idx += NT_P) {
        int i = idx >> 3, b = idx & 7;
        const float4* m  = (const float4*)(M2 + i * D_OUT);
        const float*  xr = x1b + b * SPAD;
        float at = 0.0f;
        #pragma unroll
        for (int k = 0; k < D_OUT / 4; ++k) {
            float4 mv = m[k];
            at = fmaf(mv.x, xr[4*k], fmaf(mv.y, xr[4*k+1],
                 fmaf(mv.z, xr[4*k+2], fmaf(mv.w, xr[4*k+3], at))));
        }
        xn[b * SPAD + i] = at;
    }
    __syncthreads();
    {
        const int b = tid >> 5, rr = tid & 31;
        float* row = xn + b * SPAD;
        float v0 = row[rr], v1 = row[rr + 32], v2 = row[rr + 64];
        float sum = v0 + v1 + v2, sq = fmaf(v0, v0, fmaf(v1, v1, v2 * v2));
        #pragma unroll
        for (int off = 16; off > 0; off >>= 1) {
            sum += __shfl_down(sum, off, 32);
            sq  += __shfl_down(sq,  off, 32);
        }
        sum = __shfl(sum, 0, 32); sq = __shfl(sq, 0, 32);
        float mu = sum * (1.0f/96.0f), var = fmaf(sq, 1.0f/96.0f, -(mu*mu));
        float rs = rsqrtf(var + 1e-5f);
        row[rr]      = fmaf((v0 - mu) * rs, g2[rr],      b2[rr]);
        row[rr + 32] = fmaf((v1 - mu) * rs, g2[rr + 32], b2[rr + 32]);
        row[rr + 64] = fmaf((v2 - mu) * rs, g2[rr + 64], b2[rr + 64]);
    }
    __syncthreads();
    for (int idx = tid; idx < B_SZ * D_OUT; idx += NT_P) {
        int i = idx >> 3, b = idx & 7;
        const float* wrow = w + i * SPAD;
        const float* xr   = xn + b * SPAD;
        float acc = 0.0f;
        #pragma unroll
        for (int j = 0; j < D_OUT / 4; ++j) {
            float4 wv = *(const float4*)(wrow + 4 * j);
            float4 xv = *(const float4*)(xr + 4 * j);
            acc = fmaf(wv.x, xv.x, fmaf(wv.y, xv.y, fmaf(wv.z, xv.z, fmaf(wv.w, xv.w, acc))));
        }
        out[(b * S_LEN + s) * D_OUT + i] = acc + x1b[b * SPAD + i];
    }
}

extern "C" void kernel_launch(void* const* d_in, const int* in_sizes, int n_in,
                              void* d_out, int out_size, void* d_ws, size_t ws_size,
                              hipStream_t stream) {
    const float* seq   = (const float*)d_in[0];
    const float* M1    = (const float*)d_in[1];
    const float* P1    = (const float*)d_in[2];
    const float* Wres1 = (const float*)d_in[3];
    const float* g1    = (const float*)d_in[4];
    const float* b1    = (const float*)d_in[5];
    const float* M2    = (const float*)d_in[6];
    const float* P2    = (const float*)d_in[7];
    const float* g2    = (const float*)d_in[8];
    const float* b2    = (const float*)d_in[9];
    float* out = (float*)d_out;

    const size_t w_bytes  = (size_t)2 * S_LEN * NE * sizeof(__half);      // 37.75 MB
    const size_t xt_bytes = (size_t)NROWS * D_OUT * sizeof(float);        // 3.15 MB
    const size_t need     = w_bytes + 2 * xt_bytes;
    if (ws_size >= need) {
        __half* W1 = (__half*)d_ws;
        __half* W2 = W1 + (size_t)S_LEN * NE;
        float*  XT = (float*)((char*)d_ws + w_bytes);
        float*  RS = XT + (size_t)NROWS * D_OUT;
        producer<<<dim3(NWBLK + NGBLK), dim3(NT_P), 0, stream>>>(
            P1, P2, seq, M1, Wres1, W1, W2, XT, RS);
        consumer<<<dim3(S_LEN), dim3(NT_C), 0, stream>>>(
            XT, RS, M2, g1, b1, g2, b2, W1, W2, out);
    } else {
        hier_fallback<<<dim3(S_LEN), dim3(NT_P), 0, stream>>>(
            seq, M1, P1, Wres1, g1, b1, M2, P2, g2, b2, out);
    }
}

// Round 11
// 191.520 us; speedup vs baseline: 1.3770x; 1.0122x over previous
//
#include <hip/hip_runtime.h>
#include <hip/hip_fp16.h>

#define S_LEN    1024
#define B_SZ     8
#define D_IN     64
#define D_OUT    96
#define NB       8
#define NE       (D_OUT * D_OUT)          // 9216
#define CHUNK    16                       // s-steps per recurrence chain
#define NCHUNK   (S_LEN / CHUNK)          // 64
#define NT_W     256
#define NWBLK    (NCHUNK * (NE / NT_W))   // 2304 blocks = 9/CU
#define NT_C     512                      // 8 waves = 8 batch rows
#define WP2      100                      // pitch in half2 units (400 B rows, bank-rotated)
#define SPAD     100
#define XPAD     68

__device__ __forceinline__ float cos_rev(float v) {   // cos(2*pi*v), v in revolutions
    v -= floorf(v);
    return __builtin_amdgcn_cosf(v);
}

// ---------------- w_kernel: Wc[s][e] = half2(W1, W2), standalone ----------------
// c(s+1) = 2cos(2pi/p)c(s) - c(s-1). Standalone so the GEMM branch can't inflate
// VGPR (r10: merged kernel -> 88 VGPR -> 4 waves/SIMD -> latency-stalled).
__global__ void __launch_bounds__(NT_W)
w_kernel(const float* __restrict__ P1, const float* __restrict__ P2,
         __half2* __restrict__ Wc) {
    const int c  = blockIdx.x / (NE / NT_W);
    const int eb = blockIdx.x % (NE / NT_W);
    const int e  = eb * NT_W + threadIdx.x;
    const int s0 = c * CHUNK;
    const float s0f = (float)s0;

    float p1l[NB], p2l[NB];
    *(float4*)&p1l[0] = *(const float4*)(P1 + e * NB);
    *(float4*)&p1l[4] = *(const float4*)(P1 + e * NB + 4);
    *(float4*)&p2l[0] = *(const float4*)(P2 + e * NB);
    *(float4*)&p2l[4] = *(const float4*)(P2 + e * NB + 4);

    float cc[NB], cp[NB], kk[NB];
    #pragma unroll
    for (int g = 0; g < NB; ++g) {
        const float inv = __builtin_amdgcn_rcpf((float)(e * NB + 2 + g));
        cc[g] = cos_rev(s0f * inv);
        cp[g] = cos_rev((s0f - 1.0f) * inv);
        kk[g] = 2.0f * __builtin_amdgcn_cosf(inv);   // inv <= 0.5 rev
    }

    #pragma unroll 4
    for (int s = s0; s < s0 + CHUNK; ++s) {
        float a1 = 0.0f, a2 = 0.0f;
        #pragma unroll
        for (int g = 0; g < NB; ++g) {
            a1 = fmaf(p1l[g], cc[g], a1);
            a2 = fmaf(p2l[g], cc[g], a2);
        }
        Wc[s * NE + e] = __floats2half2_rn(a1, a2);   // 4 B/lane, 256 B/wave
        #pragma unroll
        for (int g = 0; g < NB; ++g) {
            float cn = fmaf(kk[g], cc[g], -cp[g]);
            cp[g] = cc[g];
            cc[g] = cn;
        }
    }
}

// ---------------- consumer helpers ----------------
// Nk dots on the interleaved tile: LAYER selects .x (W1) or .y (W2).
template <int LAYER>
__device__ __forceinline__ float nkdot(const __half2* __restrict__ wrow,
                                       const float* __restrict__ xr) {
    float acc = 0.0f;
    #pragma unroll 6
    for (int j = 0; j < 24; ++j) {              // 4 elements per iter
        float4 raw = *(const float4*)(wrow + 4 * j);
        const __half2* hp = (const __half2*)&raw;
        float2 e0 = __half22float2(hp[0]);
        float2 e1 = __half22float2(hp[1]);
        float2 e2 = __half22float2(hp[2]);
        float2 e3 = __half22float2(hp[3]);
        float4 xv = *(const float4*)(xr + 4 * j);
        if (LAYER == 1) {
            acc = fmaf(e0.x, xv.x, acc); acc = fmaf(e1.x, xv.y, acc);
            acc = fmaf(e2.x, xv.z, acc); acc = fmaf(e3.x, xv.w, acc);
        } else {
            acc = fmaf(e0.y, xv.x, acc); acc = fmaf(e1.y, xv.y, acc);
            acc = fmaf(e2.y, xv.z, acc); acc = fmaf(e3.y, xv.w, acc);
        }
    }
    return acc;
}

// 64-dot: m from global (L1-hot matrix rows), xv from LDS (broadcast).
// unroll 4 ONLY — full unroll hoists all loads and spills (r8/r9 lesson).
__device__ float dot64(const float* __restrict__ m, const float* __restrict__ xq) {
    float acc = 0.0f;
    #pragma unroll 4
    for (int k = 0; k < 16; ++k) {
        float4 mv = *(const float4*)(m + 4 * k);
        float4 xv = *(const float4*)(xq + 4 * k);
        acc = fmaf(mv.x, xv.x, fmaf(mv.y, xv.y, fmaf(mv.z, xv.z, fmaf(mv.w, xv.w, acc))));
    }
    return acc;
}

// 96-dot: m from global (M2), xv from LDS. unroll 4 (r10-proven non-spill).
__device__ float dot96(const float* __restrict__ m, const float* __restrict__ xr) {
    float acc = 0.0f;
    #pragma unroll 4
    for (int k = 0; k < 24; ++k) {
        float4 mv = *(const float4*)(m + 4 * k);
        float4 xv = *(const float4*)(xr + 4 * k);
        acc = fmaf(mv.x, xv.x, fmaf(mv.y, xv.y, fmaf(mv.z, xv.z, fmaf(mv.w, xv.w, acc))));
    }
    return acc;
}

// ---------------- Consumer: ONE barrier, wave64 per batch row, inline layer-1 ----------------
// NO min-waves clause ((512,N) produced destructive caps in r5/r9).
__global__ void __launch_bounds__(NT_C)
consumer(const float* __restrict__ seq,
         const float* __restrict__ M1, const float* __restrict__ Wres1,
         const float* __restrict__ M2,
         const float* __restrict__ g1, const float* __restrict__ b1,
         const float* __restrict__ g2, const float* __restrict__ b2,
         const __half2* __restrict__ Wc,
         float* __restrict__ out) {
    __shared__ __align__(16) __half2 wh [D_OUT * WP2];   // 38400 B (both layers)
    __shared__ __align__(16) float   xin[B_SZ * XPAD];   //  2176 B
    __shared__ __align__(16) float   xbuf[B_SZ * SPAD];  //  3200 B -> 43776 total

    const int s    = blockIdx.x;
    const int tid  = threadIdx.x;
    const int b    = tid >> 6;
    const int lane = tid & 63;
    const bool lo  = (lane < 32);

    // stage Wc[s] (36864 B) once; stage seq rows (512 floats, one per thread)
    {
        const __half2* Ws = Wc + (size_t)s * NE;
        for (int c = tid; c < NE / 4; c += NT_C) {       // float4 = 4 elements
            int el = c * 4;
            int i = el / D_OUT, j = el - i * D_OUT;      // j multiple of 4
            *(float4*)(wh + i * WP2 + j) = *(const float4*)(Ws + el);
        }
        xin[b * XPAD + lane] = seq[((size_t)b * S_LEN + s) * D_IN + lane];
    }
    __syncthreads();   // B1 — the ONLY barrier

    const float* xq = xin + b * XPAD;
    float*       xr = xbuf + b * SPAD;   // wave-private; LDS w->r ordered in-wave

    // ---- layer-1 GEMV inline: xt_i = M1[i,:].x, rs_i = Wres1[i,:].x ----
    float xt0 = dot64(M1 + lane * D_IN, xq);
    float rs0 = dot64(Wres1 + lane * D_IN, xq);
    float xt1 = 0.0f, rs1 = 0.0f;
    if (lo) {
        xt1 = dot64(M1 + (64 + lane) * D_IN, xq);
        rs1 = dot64(Wres1 + (64 + lane) * D_IN, xq);
    }

    // ---- LN1 (in-wave) ----
    {
        float sum = xt0 + xt1;
        float sq  = fmaf(xt0, xt0, xt1 * xt1);
        #pragma unroll
        for (int off = 32; off > 0; off >>= 1) {
            sum += __shfl_down(sum, off, 64);
            sq  += __shfl_down(sq,  off, 64);
        }
        sum = __shfl(sum, 0, 64);
        sq  = __shfl(sq,  0, 64);
        const float mu  = sum * (1.0f / 96.0f);
        const float var = fmaf(sq, 1.0f / 96.0f, -(mu * mu));
        const float rst = rsqrtf(var + 1e-5f);
        xr[lane] = fmaf((xt0 - mu) * rst, g1[lane], b1[lane]);
        if (lo) xr[64 + lane] = fmaf((xt1 - mu) * rst, g1[64 + lane], b1[64 + lane]);
    }

    // ---- Nk1 + residual ----
    float x10 = rs0 + nkdot<1>(wh + lane * WP2, xr);
    float x11 = 0.0f;
    if (lo) x11 = rs1 + nkdot<1>(wh + (64 + lane) * WP2, xr);

    // publish x1 (wave-private row; all wh reads above are this wave's own)
    xr[lane] = x10;
    if (lo) xr[64 + lane] = x11;

    // ---- layer-2 GEMV: M2 rows from global (L1/L2-hot) ----
    float t0 = dot96(M2 + lane * D_OUT, xr);
    float t1 = 0.0f;
    if (lo) t1 = dot96(M2 + (64 + lane) * D_OUT, xr);

    // ---- LN2 ----
    {
        float sum = t0 + t1;
        float sq  = fmaf(t0, t0, t1 * t1);
        #pragma unroll
        for (int off = 32; off > 0; off >>= 1) {
            sum += __shfl_down(sum, off, 64);
            sq  += __shfl_down(sq,  off, 64);
        }
        sum = __shfl(sum, 0, 64);
        sq  = __shfl(sq,  0, 64);
        const float mu  = sum * (1.0f / 96.0f);
        const float var = fmaf(sq, 1.0f / 96.0f, -(mu * mu));
        const float rst = rsqrtf(var + 1e-5f);
        xr[lane] = fmaf((t0 - mu) * rst, g2[lane], b2[lane]);
        if (lo) xr[64 + lane] = fmaf((t1 - mu) * rst, g2[64 + lane], b2[64 + lane]);
    }

    // ---- Nk2 + identity residual -> out ----
    const size_t r = (size_t)b * S_LEN + s;
    out[r * D_OUT + lane] = nkdot<2>(wh + lane * WP2, xr) + x10;
    if (lo)
        out[r * D_OUT + 64 + lane] = nkdot<2>(wh + (64 + lane) * WP2, xr) + x11;
}

// ---------------- Fallback (round-1 proven kernel) if ws too small ----------------
__global__ void __launch_bounds__(NT_W)
hier_fallback(const float* __restrict__ seq,  const float* __restrict__ M1,
              const float* __restrict__ P1,   const float* __restrict__ Wres1,
              const float* __restrict__ g1,   const float* __restrict__ b1,
              const float* __restrict__ M2,   const float* __restrict__ P2,
              const float* __restrict__ g2,   const float* __restrict__ b2,
              float* __restrict__ out) {
    __shared__ __align__(16) float w[D_OUT * SPAD];
    __shared__ __align__(16) float xin[B_SZ * XPAD];
    __shared__ __align__(16) float xn [B_SZ * SPAD];
    __shared__ __align__(16) float x1b[B_SZ * SPAD];
    const int s = blockIdx.x, tid = threadIdx.x;
    const float sf = (float)s;

    for (int idx = tid; idx < B_SZ * D_IN; idx += NT_W) {
        int b = idx >> 6, k = idx & (D_IN - 1);
        xin[b * XPAD + k] = seq[(b * S_LEN + s) * D_IN + k];
    }
    for (int e = tid; e < NE; e += NT_W) {
        float pl[8];
        *(float4*)&pl[0] = *(const float4*)(P1 + e * NB);
        *(float4*)&pl[4] = *(const float4*)(P1 + e * NB + 4);
        float acc = 0.0f;
        #pragma unroll
        for (int g = 0; g < NB; ++g) {
            float v = sf * __builtin_amdgcn_rcpf((float)(e * NB + 2 + g));
            acc = fmaf(pl[g], cos_rev(v), acc);
        }
        int i = e / D_OUT;
        w[e + (SPAD - D_OUT) * i] = acc;
    }
    __syncthreads();
    for (int idx = tid; idx < B_SZ * D_OUT; idx += NT_W) {
        int i = idx >> 3, b = idx & 7;
        const float4* m  = (const float4*)(M1 + i * D_IN);
        const float4* wr = (const float4*)(Wres1 + i * D_IN);
        const float*  xr = xin + b * XPAD;
        float at = 0.0f, ar = 0.0f;
        #pragma unroll
        for (int k = 0; k < D_IN / 4; ++k) {
            float4 mv = m[k], rv = wr[k];
            float x0 = xr[4*k], x1 = xr[4*k+1], x2 = xr[4*k+2], x3 = xr[4*k+3];
            at = fmaf(mv.x, x0, fmaf(mv.y, x1, fmaf(mv.z, x2, fmaf(mv.w, x3, at))));
            ar = fmaf(rv.x, x0, fmaf(rv.y, x1, fmaf(rv.z, x2, fmaf(rv.w, x3, ar))));
        }
        xn [b * SPAD + i] = at;
        x1b[b * SPAD + i] = ar;
    }
    __syncthreads();
    {
        const int b = tid >> 5, rr = tid & 31;
        float* row = xn + b * SPAD;
        float v0 = row[rr], v1 = row[rr + 32], v2 = row[rr + 64];
        float sum = v0 + v1 + v2, sq = fmaf(v0, v0, fmaf(v1, v1, v2 * v2));
        #pragma unroll
        for (int off = 16; off > 0; off >>= 1) {
            sum += __shfl_down(sum, off, 32);
            sq  += __shfl_down(sq,  off, 32);
        }
        sum = __shfl(sum, 0, 32); sq = __shfl(sq, 0, 32);
        float mu = sum * (1.0f/96.0f), var = fmaf(sq, 1.0f/96.0f, -(mu*mu));
        float rs = rsqrtf(var + 1e-5f);
        row[rr]      = fmaf((v0 - mu) * rs, g1[rr],      b1[rr]);
        row[rr + 32] = fmaf((v1 - mu) * rs, g1[rr + 32], b1[rr + 32]);
        row[rr + 64] = fmaf((v2 - mu) * rs, g1[rr + 64], b1[rr + 64]);
    }
    __syncthreads();
    for (int idx = tid; idx < B_SZ * D_OUT; idx += NT_W) {
        int i = idx >> 3, b = idx & 7;
        const float* wrow = w + i * SPAD;
        const float* xr   = xn + b * SPAD;
        float acc = 0.0f;
        #pragma unroll
        for (int j = 0; j < D_OUT / 4; ++j) {
            float4 wv = *(const float4*)(wrow + 4 * j);
            float4 xv = *(const float4*)(xr + 4 * j);
            acc = fmaf(wv.x, xv.x, fmaf(wv.y, xv.y, fmaf(wv.z, xv.z, fmaf(wv.w, xv.w, acc))));
        }
        x1b[b * SPAD + i] += acc;
    }
    __syncthreads();
    for (int e = tid; e < NE; e += NT_W) {
        float pl[8];
        *(float4*)&pl[0] = *(const float4*)(P2 + e * NB);
        *(float4*)&pl[4] = *(const float4*)(P2 + e * NB + 4);
        float acc = 0.0f;
        #pragma unroll
        for (int g = 0; g < NB; ++g) {
            float v = sf * __builtin_amdgcn_rcpf((float)(e * NB + 2 + g));
            acc = fmaf(pl[g], cos_rev(v), acc);
        }
        int i = e / D_OUT;
        w[e + (SPAD - D_OUT) * i] = acc;
    }
    for (int idx = tid; idx < B_SZ * D_OUT; idx += NT_W) {
        int i = idx >> 3, b = idx & 7;
        const float4* m  = (const float4*)(M2 + i * D_OUT);
        const float*  xr = x1b + b * SPAD;
        float at = 0.0f;
        #pragma unroll
        for (int k = 0; k < D_OUT / 4; ++k) {
            float4 mv = m[k];
            at = fmaf(mv.x, xr[4*k], fmaf(mv.y, xr[4*k+1],
                 fmaf(mv.z, xr[4*k+2], fmaf(mv.w, xr[4*k+3], at))));
        }
        xn[b * SPAD + i] = at;
    }
    __syncthreads();
    {
        const int b = tid >> 5, rr = tid & 31;
        float* row = xn + b * SPAD;
        float v0 = row[rr], v1 = row[rr + 32], v2 = row[rr + 64];
        float sum = v0 + v1 + v2, sq = fmaf(v0, v0, fmaf(v1, v1, v2 * v2));
        #pragma unroll
        for (int off = 16; off > 0; off >>= 1) {
            sum += __shfl_down(sum, off, 32);
            sq  += __shfl_down(sq,  off, 32);
        }
        sum = __shfl(sum, 0, 32); sq = __shfl(sq, 0, 32);
        float mu = sum * (1.0f/96.0f), var = fmaf(sq, 1.0f/96.0f, -(mu*mu));
        float rs = rsqrtf(var + 1e-5f);
        row[rr]      = fmaf((v0 - mu) * rs, g2[rr],      b2[rr]);
        row[rr + 32] = fmaf((v1 - mu) * rs, g2[rr + 32], b2[rr + 32]);
        row[rr + 64] = fmaf((v2 - mu) * rs, g2[rr + 64], b2[rr + 64]);
    }
    __syncthreads();
    for (int idx = tid; idx < B_SZ * D_OUT; idx += NT_W) {
        int i = idx >> 3, b = idx & 7;
        const float* wrow = w + i * SPAD;
        const float* xr   = xn + b * SPAD;
        float acc = 0.0f;
        #pragma unroll
        for (int j = 0; j < D_OUT / 4; ++j) {
            float4 wv = *(const float4*)(wrow + 4 * j);
            float4 xv = *(const float4*)(xr + 4 * j);
            acc = fmaf(wv.x, xv.x, fmaf(wv.y, xv.y, fmaf(wv.z, xv.z, fmaf(wv.w, xv.w, acc))));
        }
        out[(b * S_LEN + s) * D_OUT + i] = acc + x1b[b * SPAD + i];
    }
}

extern "C" void kernel_launch(void* const* d_in, const int* in_sizes, int n_in,
                              void* d_out, int out_size, void* d_ws, size_t ws_size,
                              hipStream_t stream) {
    const float* seq   = (const float*)d_in[0];
    const float* M1    = (const float*)d_in[1];
    const float* P1    = (const float*)d_in[2];
    const float* Wres1 = (const float*)d_in[3];
    const float* g1    = (const float*)d_in[4];
    const float* b1    = (const float*)d_in[5];
    const float* M2    = (const float*)d_in[6];
    const float* P2    = (const float*)d_in[7];
    const float* g2    = (const float*)d_in[8];
    const float* b2    = (const float*)d_in[9];
    float* out = (float*)d_out;

    const size_t need = (size_t)S_LEN * NE * sizeof(__half2);   // 37.75 MB
    if (ws_size >= need) {
        __half2* Wc = (__half2*)d_ws;
        w_kernel<<<dim3(NWBLK), dim3(NT_W), 0, stream>>>(P1, P2, Wc);
        consumer<<<dim3(S_LEN), dim3(NT_C), 0, stream>>>(
            seq, M1, Wres1, M2, g1, b1, g2, b2, Wc, out);
    } else {
        hier_fallback<<<dim3(S_LEN), dim3(NT_W), 0, stream>>>(
            seq, M1, P1, Wres1, g1, b1, M2, P2, g2, b2, out);
    }
}

// Round 12
// 120.571 us; speedup vs baseline: 2.1873x; 1.5884x over previous
//
#include <hip/hip_runtime.h>
#include <hip/hip_fp16.h>

#define S_LEN    1024
#define B_SZ     8
#define D_IN     64
#define D_OUT    96
#define NB       8
#define NE       (D_OUT * D_OUT)          // 9216
#define CHUNK    16                       // s-steps per recurrence chain
#define NCHUNK   (S_LEN / CHUNK)          // 64
#define NT_W     256
#define NWBLK    (NCHUNK * (NE / NT_W))   // 2304 blocks = 9/CU
#define NT_C     512                      // 8 waves
#define WP2      100                      // wh pitch in half2 (400 B rows, 4-bank rotation)
#define SPAD     100                      // f32 row pitch
#define XPAD     68

__device__ __forceinline__ float cos_rev(float v) {   // cos(2*pi*v), v in revolutions
    v -= floorf(v);
    return __builtin_amdgcn_cosf(v);
}

// ---------------- w_kernel: Wc[s][e] = half2(W1, W2)  (r11-proven) ----------------
__global__ void __launch_bounds__(NT_W)
w_kernel(const float* __restrict__ P1, const float* __restrict__ P2,
         __half2* __restrict__ Wc) {
    const int c  = blockIdx.x / (NE / NT_W);
    const int eb = blockIdx.x % (NE / NT_W);
    const int e  = eb * NT_W + threadIdx.x;
    const int s0 = c * CHUNK;
    const float s0f = (float)s0;

    float p1l[NB], p2l[NB];
    *(float4*)&p1l[0] = *(const float4*)(P1 + e * NB);
    *(float4*)&p1l[4] = *(const float4*)(P1 + e * NB + 4);
    *(float4*)&p2l[0] = *(const float4*)(P2 + e * NB);
    *(float4*)&p2l[4] = *(const float4*)(P2 + e * NB + 4);

    float cc[NB], cp[NB], kk[NB];
    #pragma unroll
    for (int g = 0; g < NB; ++g) {
        const float inv = __builtin_amdgcn_rcpf((float)(e * NB + 2 + g));
        cc[g] = cos_rev(s0f * inv);
        cp[g] = cos_rev((s0f - 1.0f) * inv);
        kk[g] = 2.0f * __builtin_amdgcn_cosf(inv);   // inv <= 0.5 rev
    }

    #pragma unroll 4
    for (int s = s0; s < s0 + CHUNK; ++s) {
        float a1 = 0.0f, a2 = 0.0f;
        #pragma unroll
        for (int g = 0; g < NB; ++g) {
            a1 = fmaf(p1l[g], cc[g], a1);
            a2 = fmaf(p2l[g], cc[g], a2);
        }
        Wc[s * NE + e] = __floats2half2_rn(a1, a2);   // 4 B/lane coalesced
        #pragma unroll
        for (int g = 0; g < NB; ++g) {
            float cn = fmaf(kk[g], cc[g], -cp[g]);
            cp[g] = cc[g];
            cc[g] = cn;
        }
    }
}

// Nk dot on interleaved tile: LAYER picks .x (W1) / .y (W2). 8 lanes share wrow
// (LDS broadcast); xr rows conflict-free at SPAD stride. unroll 6 (r11: VGPR 40).
template <int LAYER>
__device__ __forceinline__ float nkdot(const __half2* __restrict__ wrow,
                                       const float* __restrict__ xr) {
    float acc = 0.0f;
    #pragma unroll 6
    for (int j = 0; j < 24; ++j) {
        float4 raw = *(const float4*)(wrow + 4 * j);
        const __half2* hp = (const __half2*)&raw;
        float2 e0 = __half22float2(hp[0]);
        float2 e1 = __half22float2(hp[1]);
        float2 e2 = __half22float2(hp[2]);
        float2 e3 = __half22float2(hp[3]);
        float4 xv = *(const float4*)(xr + 4 * j);
        if (LAYER == 1) {
            acc = fmaf(e0.x, xv.x, acc); acc = fmaf(e1.x, xv.y, acc);
            acc = fmaf(e2.x, xv.z, acc); acc = fmaf(e3.x, xv.w, acc);
        } else {
            acc = fmaf(e0.y, xv.x, acc); acc = fmaf(e1.y, xv.y, acc);
            acc = fmaf(e2.y, xv.z, acc); acc = fmaf(e3.y, xv.w, acc);
        }
    }
    return acc;
}

// ---------------- Consumer: r6 structure, single interleaved W stage ----------------
// r6 mapping everywhere (i=idx>>3, b=idx&7): 8 lanes share each matrix/W row
// (coalesced/broadcast) — r11's lane-per-row gather was the 112 us pathology.
__global__ void __launch_bounds__(NT_C)
consumer(const float* __restrict__ seq,
         const float* __restrict__ M1, const float* __restrict__ Wres1,
         const float* __restrict__ M2,
         const float* __restrict__ g1, const float* __restrict__ b1,
         const float* __restrict__ g2, const float* __restrict__ b2,
         const __half2* __restrict__ Wc,
         float* __restrict__ out) {
    __shared__ __align__(16) __half2 wh [D_OUT * WP2];   // 38400 B (both layers)
    __shared__ __align__(16) float   xn [B_SZ * SPAD];   //  3200 B
    __shared__ __align__(16) float   x1b[B_SZ * SPAD];   //  3200 B; doubles as xin pre-Nk1
    // total 44800 B -> 3 blocks/CU (LDS-bound)

    const int s   = blockIdx.x;
    const int tid = threadIdx.x;

    // stage Wc[s] (36864 B) once + seq rows into x1b's alias space
    {
        const __half2* Ws = Wc + (size_t)s * NE;
        for (int c = tid; c < NE / 4; c += NT_C) {
            int el = c * 4;
            int i = el / D_OUT, j = el - i * D_OUT;   // j multiple of 4
            *(float4*)(wh + i * WP2 + j) = *(const float4*)(Ws + el);
        }
        int b = tid >> 6, k = tid & 63;
        x1b[b * SPAD + k] = seq[((size_t)b * S_LEN + s) * D_IN + k];   // xin alias
    }
    __syncthreads();   // B1

    // ---- GEMV1: xt = seq@M1^T -> xn;  rs = seq@Wres1^T -> REGISTERS ----
    float ar0 = 0.0f, ar1 = 0.0f;
    for (int pass = 0; pass < 2; ++pass) {
        int idx = tid + pass * NT_C;
        if (idx >= B_SZ * D_OUT) break;
        int i = idx >> 3, b = idx & 7;
        const float4* m  = (const float4*)(M1 + i * D_IN);
        const float4* wr = (const float4*)(Wres1 + i * D_IN);
        const float*  xr = x1b + b * SPAD;   // xin alias
        float at = 0.0f, ar = 0.0f;
        #pragma unroll
        for (int k = 0; k < D_IN / 4; ++k) {
            float4 mv = m[k], rv = wr[k];
            float x0 = xr[4*k], x1 = xr[4*k+1], x2 = xr[4*k+2], x3 = xr[4*k+3];
            at = fmaf(mv.x, x0, fmaf(mv.y, x1, fmaf(mv.z, x2, fmaf(mv.w, x3, at))));
            ar = fmaf(rv.x, x0, fmaf(rv.y, x1, fmaf(rv.z, x2, fmaf(rv.w, x3, ar))));
        }
        xn[b * SPAD + i] = at;
        if (pass == 0) ar0 = ar; else ar1 = ar;
    }
    __syncthreads();   // B2  (xin alias dead from here)

    // ---- LN1: wave64 per batch row ----
    {
        const int b = tid >> 6, lane = tid & 63;
        const bool lo = (lane < 32);
        float* row = xn + b * SPAD;
        float v0 = row[lane];
        float v1 = lo ? row[64 + lane] : 0.0f;
        float sum = v0 + v1, sq = fmaf(v0, v0, v1 * v1);
        #pragma unroll
        for (int off = 32; off > 0; off >>= 1) {
            sum += __shfl_down(sum, off, 64);
            sq  += __shfl_down(sq,  off, 64);
        }
        sum = __shfl(sum, 0, 64);
        sq  = __shfl(sq,  0, 64);
        const float mu  = sum * (1.0f / 96.0f);
        const float var = fmaf(sq, 1.0f / 96.0f, -(mu * mu));
        const float rs  = rsqrtf(var + 1e-5f);
        row[lane] = fmaf((v0 - mu) * rs, g1[lane], b1[lane]);
        if (lo) row[64 + lane] = fmaf((v1 - mu) * rs, g1[64 + lane], b1[64 + lane]);
    }
    __syncthreads();   // B3

    // ---- Nk1 + residual(regs) -> x1b ----
    for (int pass = 0; pass < 2; ++pass) {
        int idx = tid + pass * NT_C;
        if (idx >= B_SZ * D_OUT) break;
        int i = idx >> 3, b = idx & 7;
        float ar = (pass == 0) ? ar0 : ar1;
        x1b[b * SPAD + i] = ar + nkdot<1>(wh + i * WP2, xn + b * SPAD);
    }
    __syncthreads();   // B4

    // ---- GEMV2: xt2 = x1 @ M2^T -> xn ----
    for (int pass = 0; pass < 2; ++pass) {
        int idx = tid + pass * NT_C;
        if (idx >= B_SZ * D_OUT) break;
        int i = idx >> 3, b = idx & 7;
        const float4* m  = (const float4*)(M2 + i * D_OUT);
        const float*  xr = x1b + b * SPAD;
        float at = 0.0f;
        #pragma unroll
        for (int k = 0; k < D_OUT / 4; ++k) {
            float4 mv = m[k];
            at = fmaf(mv.x, xr[4*k], fmaf(mv.y, xr[4*k+1],
                 fmaf(mv.z, xr[4*k+2], fmaf(mv.w, xr[4*k+3], at))));
        }
        xn[b * SPAD + i] = at;
    }
    __syncthreads();   // B5

    // ---- LN2 ----
    {
        const int b = tid >> 6, lane = tid & 63;
        const bool lo = (lane < 32);
        float* row = xn + b * SPAD;
        float v0 = row[lane];
        float v1 = lo ? row[64 + lane] : 0.0f;
        float sum = v0 + v1, sq = fmaf(v0, v0, v1 * v1);
        #pragma unroll
        for (int off = 32; off > 0; off >>= 1) {
            sum += __shfl_down(sum, off, 64);
            sq  += __shfl_down(sq,  off, 64);
        }
        sum = __shfl(sum, 0, 64);
        sq  = __shfl(sq,  0, 64);
        const float mu  = sum * (1.0f / 96.0f);
        const float var = fmaf(sq, 1.0f / 96.0f, -(mu * mu));
        const float rs  = rsqrtf(var + 1e-5f);
        row[lane] = fmaf((v0 - mu) * rs, g2[lane], b2[lane]);
        if (lo) row[64 + lane] = fmaf((v1 - mu) * rs, g2[64 + lane], b2[64 + lane]);
    }
    __syncthreads();   // B6

    // ---- Nk2 + identity residual -> out ----
    for (int pass = 0; pass < 2; ++pass) {
        int idx = tid + pass * NT_C;
        if (idx >= B_SZ * D_OUT) break;
        int i = idx >> 3, b = idx & 7;
        float acc = nkdot<2>(wh + i * WP2, xn + b * SPAD);
        out[((size_t)b * S_LEN + s) * D_OUT + i] = acc + x1b[b * SPAD + i];
    }
}

// ---------------- Fallback (round-1 proven kernel) if ws too small ----------------
__global__ void __launch_bounds__(NT_W)
hier_fallback(const float* __restrict__ seq,  const float* __restrict__ M1,
              const float* __restrict__ P1,   const float* __restrict__ Wres1,
              const float* __restrict__ g1,   const float* __restrict__ b1,
              const float* __restrict__ M2,   const float* __restrict__ P2,
              const float* __restrict__ g2,   const float* __restrict__ b2,
              float* __restrict__ out) {
    __shared__ __align__(16) float w[D_OUT * SPAD];
    __shared__ __align__(16) float xin[B_SZ * XPAD];
    __shared__ __align__(16) float xn [B_SZ * SPAD];
    __shared__ __align__(16) float x1b[B_SZ * SPAD];
    const int s = blockIdx.x, tid = threadIdx.x;
    const float sf = (float)s;

    for (int idx = tid; idx < B_SZ * D_IN; idx += NT_W) {
        int b = idx >> 6, k = idx & (D_IN - 1);
        xin[b * XPAD + k] = seq[(b * S_LEN + s) * D_IN + k];
    }
    for (int e = tid; e < NE; e += NT_W) {
        float pl[8];
        *(float4*)&pl[0] = *(const float4*)(P1 + e * NB);
        *(float4*)&pl[4] = *(const float4*)(P1 + e * NB + 4);
        float acc = 0.0f;
        #pragma unroll
        for (int g = 0; g < NB; ++g) {
            float v = sf * __builtin_amdgcn_rcpf((float)(e * NB + 2 + g));
            acc = fmaf(pl[g], cos_rev(v), acc);
        }
        int i = e / D_OUT;
        w[e + (SPAD - D_OUT) * i] = acc;
    }
    __syncthreads();
    for (int idx = tid; idx < B_SZ * D_OUT; idx += NT_W) {
        int i = idx >> 3, b = idx & 7;
        const float4* m  = (const float4*)(M1 + i * D_IN);
        const float4* wr = (const float4*)(Wres1 + i * D_IN);
        const float*  xr = xin + b * XPAD;
        float at = 0.0f, ar = 0.0f;
        #pragma unroll
        for (int k = 0; k < D_IN / 4; ++k) {
            float4 mv = m[k], rv = wr[k];
            float x0 = xr[4*k], x1 = xr[4*k+1], x2 = xr[4*k+2], x3 = xr[4*k+3];
            at = fmaf(mv.x, x0, fmaf(mv.y, x1, fmaf(mv.z, x2, fmaf(mv.w, x3, at))));
            ar = fmaf(rv.x, x0, fmaf(rv.y, x1, fmaf(rv.z, x2, fmaf(rv.w, x3, ar))));
        }
        xn [b * SPAD + i] = at;
        x1b[b * SPAD + i] = ar;
    }
    __syncthreads();
    {
        const int b = tid >> 5, rr = tid & 31;
        float* row = xn + b * SPAD;
        float v0 = row[rr], v1 = row[rr + 32], v2 = row[rr + 64];
        float sum = v0 + v1 + v2, sq = fmaf(v0, v0, fmaf(v1, v1, v2 * v2));
        #pragma unroll
        for (int off = 16; off > 0; off >>= 1) {
            sum += __shfl_down(sum, off, 32);
            sq  += __shfl_down(sq,  off, 32);
        }
        sum = __shfl(sum, 0, 32); sq = __shfl(sq, 0, 32);
        float mu = sum * (1.0f/96.0f), var = fmaf(sq, 1.0f/96.0f, -(mu*mu));
        float rs = rsqrtf(var + 1e-5f);
        row[rr]      = fmaf((v0 - mu) * rs, g1[rr],      b1[rr]);
        row[rr + 32] = fmaf((v1 - mu) * rs, g1[rr + 32], b1[rr + 32]);
        row[rr + 64] = fmaf((v2 - mu) * rs, g1[rr + 64], b1[rr + 64]);
    }
    __syncthreads();
    for (int idx = tid; idx < B_SZ * D_OUT; idx += NT_W) {
        int i = idx >> 3, b = idx & 7;
        const float* wrow = w + i * SPAD;
        const float* xr   = xn + b * SPAD;
        float acc = 0.0f;
        #pragma unroll
        for (int j = 0; j < D_OUT / 4; ++j) {
            float4 wv = *(const float4*)(wrow + 4 * j);
            float4 xv = *(const float4*)(xr + 4 * j);
            acc = fmaf(wv.x, xv.x, fmaf(wv.y, xv.y, fmaf(wv.z, xv.z, fmaf(wv.w, xv.w, acc))));
        }
        x1b[b * SPAD + i] += acc;
    }
    __syncthreads();
    for (int e = tid; e < NE; e += NT_W) {
        float pl[8];
        *(float4*)&pl[0] = *(const float4*)(P2 + e * NB);
        *(float4*)&pl[4] = *(const float4*)(P2 + e * NB + 4);
        float acc = 0.0f;
        #pragma unroll
        for (int g = 0; g < NB; ++g) {
            float v = sf * __builtin_amdgcn_rcpf((float)(e * NB + 2 + g));
            acc = fmaf(pl[g], cos_rev(v), acc);
        }
        int i = e / D_OUT;
        w[e + (SPAD - D_OUT) * i] = acc;
    }
    for (int idx = tid; idx < B_SZ * D_OUT; idx += NT_W) {
        int i = idx >> 3, b = idx & 7;
        const float4* m  = (const float4*)(M2 + i * D_OUT);
        const float*  xr = x1b + b * SPAD;
        float at = 0.0f;
        #pragma unroll
        for (int k = 0; k < D_OUT / 4; ++k) {
            float4 mv = m[k];
            at = fmaf(mv.x, xr[4*k], fmaf(mv.y, xr[4*k+1],
                 fmaf(mv.z, xr[4*k+2], fmaf(mv.w, xr[4*k+3], at))));
        }
        xn[b * SPAD + i] = at;
    }
    __syncthreads();
    {
        const int b = tid >> 5, rr = tid & 31;
        float* row = xn + b * SPAD;
        float v0 = row[rr], v1 = row[rr + 32], v2 = row[rr + 64];
        float sum = v0 + v1 + v2, sq = fmaf(v0, v0, fmaf(v1, v1, v2 * v2));
        #pragma unroll
        for (int off = 16; off > 0; off >>= 1) {
            sum += __shfl_down(sum, off, 32);
            sq  += __shfl_down(sq,  off, 32);
        }
        sum = __shfl(sum, 0, 32); sq = __shfl(sq, 0, 32);
        float mu = sum * (1.0f/96.0f), var = fmaf(sq, 1.0f/96.0f, -(mu*mu));
        float rs = rsqrtf(var + 1e-5f);
        row[rr]      = fmaf((v0 - mu) * rs, g2[rr],      b2[rr]);
        row[rr + 32] = fmaf((v1 - mu) * rs, g2[rr + 32], b2[rr + 32]);
        row[rr + 64] = fmaf((v2 - mu) * rs, g2[rr + 64], b2[rr + 64]);
    }
    __syncthreads();
    for (int idx = tid; idx < B_SZ * D_OUT; idx += NT_W) {
        int i = idx >> 3, b = idx & 7;
        const float* wrow = w + i * SPAD;
        const float* xr   = xn + b * SPAD;
        float acc = 0.0f;
        #pragma unroll
        for (int j = 0; j < D_OUT / 4; ++j) {
            float4 wv = *(const float4*)(wrow + 4 * j);
            float4 xv = *(const float4*)(xr + 4 * j);
            acc = fmaf(wv.x, xv.x, fmaf(wv.y, xv.y, fmaf(wv.z, xv.z, fmaf(wv.w, xv.w, acc))));
        }
        out[(b * S_LEN + s) * D_OUT + i] = acc + x1b[b * SPAD + i];
    }
}

extern "C" void kernel_launch(void* const* d_in, const int* in_sizes, int n_in,
                              void* d_out, int out_size, void* d_ws, size_t ws_size,
                              hipStream_t stream) {
    const float* seq   = (const float*)d_in[0];
    const float* M1    = (const float*)d_in[1];
    const float* P1    = (const float*)d_in[2];
    const float* Wres1 = (const float*)d_in[3];
    const float* g1    = (const float*)d_in[4];
    const float* b1    = (const float*)d_in[5];
    const float* M2    = (const float*)d_in[6];
    const float* P2    = (const float*)d_in[7];
    const float* g2    = (const float*)d_in[8];
    const float* b2    = (const float*)d_in[9];
    float* out = (float*)d_out;

    const size_t need = (size_t)S_LEN * NE * sizeof(__half2);   // 37.75 MB
    if (ws_size >= need) {
        __half2* Wc = (__half2*)d_ws;
        w_kernel<<<dim3(NWBLK), dim3(NT_W), 0, stream>>>(P1, P2, Wc);
        consumer<<<dim3(S_LEN), dim3(NT_C), 0, stream>>>(
            seq, M1, Wres1, M2, g1, b1, g2, b2, Wc, out);
    } else {
        hier_fallback<<<dim3(S_LEN), dim3(NT_W), 0, stream>>>(
            seq, M1, P1, Wres1, g1, b1, M2, P2, g2, b2, out);
    }
}

// Round 13
// 120.121 us; speedup vs baseline: 2.1955x; 1.0037x over previous
//
#include <hip/hip_runtime.h>
#include <hip/hip_fp16.h>

#define S_LEN    1024
#define B_SZ     8
#define D_IN     64
#define D_OUT    96
#define NB       8
#define NE       (D_OUT * D_OUT)          // 9216
#define CHUNK    16                       // s-steps per recurrence chain
#define NCHUNK   (S_LEN / CHUNK)          // 64
#define NT_W     256
#define NWBLK    (NCHUNK * (NE / NT_W))   // 2304 blocks = 9/CU
#define NT_C     512                      // 8 waves
#define HPAD     104                      // f16 row pitch (52 words: 8-row quads tile 32 banks)
#define SPAD     100                      // f32 row pitch
#define XPAD     68

__device__ __forceinline__ float cos_rev(float v) {   // cos(2*pi*v), v in revolutions
    v -= floorf(v);
    return __builtin_amdgcn_cosf(v);
}

// ---------------- w_kernel: planar W1, W2 (f16) via cosine recurrence ----------------
__global__ void __launch_bounds__(NT_W)
w_kernel(const float* __restrict__ P1, const float* __restrict__ P2,
         __half* __restrict__ W1, __half* __restrict__ W2) {
    const int c  = blockIdx.x / (NE / NT_W);
    const int eb = blockIdx.x % (NE / NT_W);
    const int e  = eb * NT_W + threadIdx.x;
    const int s0 = c * CHUNK;
    const float s0f = (float)s0;

    float p1l[NB], p2l[NB];
    *(float4*)&p1l[0] = *(const float4*)(P1 + e * NB);
    *(float4*)&p1l[4] = *(const float4*)(P1 + e * NB + 4);
    *(float4*)&p2l[0] = *(const float4*)(P2 + e * NB);
    *(float4*)&p2l[4] = *(const float4*)(P2 + e * NB + 4);

    float cc[NB], cp[NB], kk[NB];
    #pragma unroll
    for (int g = 0; g < NB; ++g) {
        const float inv = __builtin_amdgcn_rcpf((float)(e * NB + 2 + g));
        cc[g] = cos_rev(s0f * inv);
        cp[g] = cos_rev((s0f - 1.0f) * inv);
        kk[g] = 2.0f * __builtin_amdgcn_cosf(inv);   // inv <= 0.5 rev
    }

    #pragma unroll 4
    for (int s = s0; s < s0 + CHUNK; ++s) {
        float a1 = 0.0f, a2 = 0.0f;
        #pragma unroll
        for (int g = 0; g < NB; ++g) {
            a1 = fmaf(p1l[g], cc[g], a1);
            a2 = fmaf(p2l[g], cc[g], a2);
        }
        W1[s * NE + e] = __float2half(a1);   // coalesced 2B/lane
        W2[s * NE + e] = __float2half(a2);
        #pragma unroll
        for (int g = 0; g < NB; ++g) {
            float cn = fmaf(kk[g], cc[g], -cp[g]);
            cp[g] = cc[g];
            cc[g] = cn;
        }
    }
}

// Nk dot: planar f16 W row (LDS, 8 lanes share -> broadcast) x f32 x-row.
// Two 6-chunk halves bound in-flight LDS-load registers (r6-proven).
__device__ __forceinline__ float nkdot(const __half* __restrict__ wrow,
                                       const float* __restrict__ xr) {
    float acc = 0.0f;
    #pragma unroll
    for (int h = 0; h < 2; ++h) {
        #pragma unroll
        for (int j = h * 6; j < h * 6 + 6; ++j) {
            float4 raw = *(const float4*)(wrow + 8 * j);
            const __half2* hp = (const __half2*)&raw;
            float2 c0 = __half22float2(hp[0]);
            float2 c1 = __half22float2(hp[1]);
            float2 c2 = __half22float2(hp[2]);
            float2 c3 = __half22float2(hp[3]);
            float4 x0 = *(const float4*)(xr + 8 * j);
            float4 x1 = *(const float4*)(xr + 8 * j + 4);
            acc = fmaf(c0.x, x0.x, acc); acc = fmaf(c0.y, x0.y, acc);
            acc = fmaf(c1.x, x0.z, acc); acc = fmaf(c1.y, x0.w, acc);
            acc = fmaf(c2.x, x1.x, acc); acc = fmaf(c2.y, x1.y, acc);
            acc = fmaf(c3.x, x1.z, acc); acc = fmaf(c3.y, x1.w, acc);
        }
    }
    return acc;
}

__device__ __forceinline__ void stage_W(__half* __restrict__ wh,
                                        const __half* __restrict__ Wg,
                                        int tid) {
    for (int cidx = tid; cidx < NE / 8; cidx += NT_C) {   // 1152 float4 chunks
        const int i = cidx / 12;
        const int j = (cidx % 12) * 8;
        *(float4*)(wh + i * HPAD + j) = *(const float4*)(Wg + cidx * 8);
    }
}

// ---------------- Consumer: planar wh staged twice, 26.4 KB LDS -> 4 blocks/CU ----------------
// 512 thr = 8 waves; 1024 blocks = exactly 4/CU, zero tail, 32 waves/CU.
// NO min-waves clause ((512,N) produced destructive VGPR caps in r5/r9).
__global__ void __launch_bounds__(NT_C)
consumer(const float* __restrict__ seq,
         const float* __restrict__ M1, const float* __restrict__ Wres1,
         const float* __restrict__ M2,
         const float* __restrict__ g1, const float* __restrict__ b1,
         const float* __restrict__ g2, const float* __restrict__ b2,
         const __half* __restrict__ W1g, const __half* __restrict__ W2g,
         float* __restrict__ out) {
    __shared__ __align__(16) __half wh [D_OUT * HPAD];   // 19968 B (one layer at a time)
    __shared__ __align__(16) float  xn [B_SZ * SPAD];    //  3200 B
    __shared__ __align__(16) float  x1b[B_SZ * SPAD];    //  3200 B; xin alias pre-Nk1
    // total 26368 B

    const int s   = blockIdx.x;
    const int tid = threadIdx.x;

    // stage W1[s] + seq rows (into x1b alias space)
    stage_W(wh, W1g + (size_t)s * NE, tid);
    {
        int b = tid >> 6, k = tid & 63;
        x1b[b * SPAD + k] = seq[((size_t)b * S_LEN + s) * D_IN + k];   // xin alias
    }
    __syncthreads();   // B1

    // ---- GEMV1: xt = seq@M1^T -> xn;  rs = seq@Wres1^T -> registers ----
    float ar0 = 0.0f, ar1 = 0.0f;
    for (int pass = 0; pass < 2; ++pass) {
        int idx = tid + pass * NT_C;
        if (idx >= B_SZ * D_OUT) break;
        int i = idx >> 3, b = idx & 7;
        const float4* m  = (const float4*)(M1 + i * D_IN);
        const float4* wr = (const float4*)(Wres1 + i * D_IN);
        const float*  xr = x1b + b * SPAD;   // xin alias
        float at = 0.0f, ar = 0.0f;
        #pragma unroll
        for (int k = 0; k < D_IN / 4; ++k) {
            float4 mv = m[k], rv = wr[k];
            float x0 = xr[4*k], x1 = xr[4*k+1], x2 = xr[4*k+2], x3 = xr[4*k+3];
            at = fmaf(mv.x, x0, fmaf(mv.y, x1, fmaf(mv.z, x2, fmaf(mv.w, x3, at))));
            ar = fmaf(rv.x, x0, fmaf(rv.y, x1, fmaf(rv.z, x2, fmaf(rv.w, x3, ar))));
        }
        xn[b * SPAD + i] = at;
        if (pass == 0) ar0 = ar; else ar1 = ar;
    }
    __syncthreads();   // B2  (xin alias dead from here)

    // ---- LN1: wave64 per batch row ----
    {
        const int b = tid >> 6, lane = tid & 63;
        const bool lo = (lane < 32);
        float* row = xn + b * SPAD;
        float v0 = row[lane];
        float v1 = lo ? row[64 + lane] : 0.0f;
        float sum = v0 + v1, sq = fmaf(v0, v0, v1 * v1);
        #pragma unroll
        for (int off = 32; off > 0; off >>= 1) {
            sum += __shfl_down(sum, off, 64);
            sq  += __shfl_down(sq,  off, 64);
        }
        sum = __shfl(sum, 0, 64);
        sq  = __shfl(sq,  0, 64);
        const float mu  = sum * (1.0f / 96.0f);
        const float var = fmaf(sq, 1.0f / 96.0f, -(mu * mu));
        const float rs  = rsqrtf(var + 1e-5f);
        row[lane] = fmaf((v0 - mu) * rs, g1[lane], b1[lane]);
        if (lo) row[64 + lane] = fmaf((v1 - mu) * rs, g1[64 + lane], b1[64 + lane]);
    }
    __syncthreads();   // B3

    // ---- Nk1 + residual(regs) -> x1b ----
    for (int pass = 0; pass < 2; ++pass) {
        int idx = tid + pass * NT_C;
        if (idx >= B_SZ * D_OUT) break;
        int i = idx >> 3, b = idx & 7;
        float ar = (pass == 0) ? ar0 : ar1;
        x1b[b * SPAD + i] = ar + nkdot(wh + i * HPAD, xn + b * SPAD);
    }
    __syncthreads();   // B4: W1 reads + x1b writes complete

    // restage wh <- W2[s]; GEMV2 overlaps (doesn't touch wh), B5 covers both.
    stage_W(wh, W2g + (size_t)s * NE, tid);

    // ---- GEMV2: xt2 = x1 @ M2^T -> xn ----
    for (int pass = 0; pass < 2; ++pass) {
        int idx = tid + pass * NT_C;
        if (idx >= B_SZ * D_OUT) break;
        int i = idx >> 3, b = idx & 7;
        const float4* m  = (const float4*)(M2 + i * D_OUT);
        const float*  xr = x1b + b * SPAD;
        float at = 0.0f;
        #pragma unroll
        for (int k = 0; k < D_OUT / 4; ++k) {
            float4 mv = m[k];
            at = fmaf(mv.x, xr[4*k], fmaf(mv.y, xr[4*k+1],
                 fmaf(mv.z, xr[4*k+2], fmaf(mv.w, xr[4*k+3], at))));
        }
        xn[b * SPAD + i] = at;
    }
    __syncthreads();   // B5

    // ---- LN2 ----
    {
        const int b = tid >> 6, lane = tid & 63;
        const bool lo = (lane < 32);
        float* row = xn + b * SPAD;
        float v0 = row[lane];
        float v1 = lo ? row[64 + lane] : 0.0f;
        float sum = v0 + v1, sq = fmaf(v0, v0, v1 * v1);
        #pragma unroll
        for (int off = 32; off > 0; off >>= 1) {
            sum += __shfl_down(sum, off, 64);
            sq  += __shfl_down(sq,  off, 64);
        }
        sum = __shfl(sum, 0, 64);
        sq  = __shfl(sq,  0, 64);
        const float mu  = sum * (1.0f / 96.0f);
        const float var = fmaf(sq, 1.0f / 96.0f, -(mu * mu));
        const float rs  = rsqrtf(var + 1e-5f);
        row[lane] = fmaf((v0 - mu) * rs, g2[lane], b2[lane]);
        if (lo) row[64 + lane] = fmaf((v1 - mu) * rs, g2[64 + lane], b2[64 + lane]);
    }
    __syncthreads();   // B6

    // ---- Nk2 + identity residual -> out ----
    for (int pass = 0; pass < 2; ++pass) {
        int idx = tid + pass * NT_C;
        if (idx >= B_SZ * D_OUT) break;
        int i = idx >> 3, b = idx & 7;
        float acc = nkdot(wh + i * HPAD, xn + b * SPAD);
        out[((size_t)b * S_LEN + s) * D_OUT + i] = acc + x1b[b * SPAD + i];
    }
}

// ---------------- Fallback (round-1 proven kernel) if ws too small ----------------
__global__ void __launch_bounds__(NT_W)
hier_fallback(const float* __restrict__ seq,  const float* __restrict__ M1,
              const float* __restrict__ P1,   const float* __restrict__ Wres1,
              const float* __restrict__ g1,   const float* __restrict__ b1,
              const float* __restrict__ M2,   const float* __restrict__ P2,
              const float* __restrict__ g2,   const float* __restrict__ b2,
              float* __restrict__ out) {
    __shared__ __align__(16) float w[D_OUT * SPAD];
    __shared__ __align__(16) float xin[B_SZ * XPAD];
    __shared__ __align__(16) float xn [B_SZ * SPAD];
    __shared__ __align__(16) float x1b[B_SZ * SPAD];
    const int s = blockIdx.x, tid = threadIdx.x;
    const float sf = (float)s;

    for (int idx = tid; idx < B_SZ * D_IN; idx += NT_W) {
        int b = idx >> 6, k = idx & (D_IN - 1);
        xin[b * XPAD + k] = seq[(b * S_LEN + s) * D_IN + k];
    }
    for (int e = tid; e < NE; e += NT_W) {
        float pl[8];
        *(float4*)&pl[0] = *(const float4*)(P1 + e * NB);
        *(float4*)&pl[4] = *(const float4*)(P1 + e * NB + 4);
        float acc = 0.0f;
        #pragma unroll
        for (int g = 0; g < NB; ++g) {
            float v = sf * __builtin_amdgcn_rcpf((float)(e * NB + 2 + g));
            acc = fmaf(pl[g], cos_rev(v), acc);
        }
        int i = e / D_OUT;
        w[e + (SPAD - D_OUT) * i] = acc;
    }
    __syncthreads();
    for (int idx = tid; idx < B_SZ * D_OUT; idx += NT_W) {
        int i = idx >> 3, b = idx & 7;
        const float4* m  = (const float4*)(M1 + i * D_IN);
        const float4* wr = (const float4*)(Wres1 + i * D_IN);
        const float*  xr = xin + b * XPAD;
        float at = 0.0f, ar = 0.0f;
        #pragma unroll
        for (int k = 0; k < D_IN / 4; ++k) {
            float4 mv = m[k], rv = wr[k];
            float x0 = xr[4*k], x1 = xr[4*k+1], x2 = xr[4*k+2], x3 = xr[4*k+3];
            at = fmaf(mv.x, x0, fmaf(mv.y, x1, fmaf(mv.z, x2, fmaf(mv.w, x3, at))));
            ar = fmaf(rv.x, x0, fmaf(rv.y, x1, fmaf(rv.z, x2, fmaf(rv.w, x3, ar))));
        }
        xn [b * SPAD + i] = at;
        x1b[b * SPAD + i] = ar;
    }
    __syncthreads();
    {
        const int b = tid >> 5, rr = tid & 31;
        float* row = xn + b * SPAD;
        float v0 = row[rr], v1 = row[rr + 32], v2 = row[rr + 64];
        float sum = v0 + v1 + v2, sq = fmaf(v0, v0, fmaf(v1, v1, v2 * v2));
        #pragma unroll
        for (int off = 16; off > 0; off >>= 1) {
            sum += __shfl_down(sum, off, 32);
            sq  += __shfl_down(sq,  off, 32);
        }
        sum = __shfl(sum, 0, 32); sq = __shfl(sq, 0, 32);
        float mu = sum * (1.0f/96.0f), var = fmaf(sq, 1.0f/96.0f, -(mu*mu));
        float rs = rsqrtf(var + 1e-5f);
        row[rr]      = fmaf((v0 - mu) * rs, g1[rr],      b1[rr]);
        row[rr + 32] = fmaf((v1 - mu) * rs, g1[rr + 32], b1[rr + 32]);
        row[rr + 64] = fmaf((v2 - mu) * rs, g1[rr + 64], b1[rr + 64]);
    }
    __syncthreads();
    for (int idx = tid; idx < B_SZ * D_OUT; idx += NT_W) {
        int i = idx >> 3, b = idx & 7;
        const float* wrow = w + i * SPAD;
        const float* xr   = xn + b * SPAD;
        float acc = 0.0f;
        #pragma unroll
        for (int j = 0; j < D_OUT / 4; ++j) {
            float4 wv = *(const float4*)(wrow + 4 * j);
            float4 xv = *(const float4*)(xr + 4 * j);
            acc = fmaf(wv.x, xv.x, fmaf(wv.y, xv.y, fmaf(wv.z, xv.z, fmaf(wv.w, xv.w, acc))));
        }
        x1b[b * SPAD + i] += acc;
    }
    __syncthreads();
    for (int e = tid; e < NE; e += NT_W) {
        float pl[8];
        *(float4*)&pl[0] = *(const float4*)(P2 + e * NB);
        *(float4*)&pl[4] = *(const float4*)(P2 + e * NB + 4);
        float acc = 0.0f;
        #pragma unroll
        for (int g = 0; g < NB; ++g) {
            float v = sf * __builtin_amdgcn_rcpf((float)(e * NB + 2 + g));
            acc = fmaf(pl[g], cos_rev(v), acc);
        }
        int i = e / D_OUT;
        w[e + (SPAD - D_OUT) * i] = acc;
    }
    for (int idx = tid; idx < B_SZ * D_OUT; idx += NT_W) {
        int i = idx >> 3, b = idx & 7;
        const float4* m  = (const float4*)(M2 + i * D_OUT);
        const float*  xr = x1b + b * SPAD;
        float at = 0.0f;
        #pragma unroll
        for (int k = 0; k < D_OUT / 4; ++k) {
            float4 mv = m[k];
            at = fmaf(mv.x, xr[4*k], fmaf(mv.y, xr[4*k+1],
                 fmaf(mv.z, xr[4*k+2], fmaf(mv.w, xr[4*k+3], at))));
        }
        xn[b * SPAD + i] = at;
    }
    __syncthreads();
    {
        const int b = tid >> 5, rr = tid & 31;
        float* row = xn + b * SPAD;
        float v0 = row[rr], v1 = row[rr + 32], v2 = row[rr + 64];
        float sum = v0 + v1 + v2, sq = fmaf(v0, v0, fmaf(v1, v1, v2 * v2));
        #pragma unroll
        for (int off = 16; off > 0; off >>= 1) {
            sum += __shfl_down(sum, off, 32);
            sq  += __shfl_down(sq,  off, 32);
        }
        sum = __shfl(sum, 0, 32); sq = __shfl(sq, 0, 32);
        float mu = sum * (1.0f/96.0f), var = fmaf(sq, 1.0f/96.0f, -(mu*mu));
        float rs = rsqrtf(var + 1e-5f);
        row[rr]      = fmaf((v0 - mu) * rs, g2[rr],      b2[rr]);
        row[rr + 32] = fmaf((v1 - mu) * rs, g2[rr + 32], b2[rr + 32]);
        row[rr + 64] = fmaf((v2 - mu) * rs, g2[rr + 64], b2[rr + 64]);
    }
    __syncthreads();
    for (int idx = tid; idx < B_SZ * D_OUT; idx += NT_W) {
        int i = idx >> 3, b = idx & 7;
        const float* wrow = w + i * SPAD;
        const float* xr   = xn + b * SPAD;
        float acc = 0.0f;
        #pragma unroll
        for (int j = 0; j < D_OUT / 4; ++j) {
            float4 wv = *(const float4*)(wrow + 4 * j);
            float4 xv = *(const float4*)(xr + 4 * j);
            acc = fmaf(wv.x, xv.x, fmaf(wv.y, xv.y, fmaf(wv.z, xv.z, fmaf(wv.w, xv.w, acc))));
        }
        out[(b * S_LEN + s) * D_OUT + i] = acc + x1b[b * SPAD + i];
    }
}

extern "C" void kernel_launch(void* const* d_in, const int* in_sizes, int n_in,
                              void* d_out, int out_size, void* d_ws, size_t ws_size,
                              hipStream_t stream) {
    const float* seq   = (const float*)d_in[0];
    const float* M1    = (const float*)d_in[1];
    const float* P1    = (const float*)d_in[2];
    const float* Wres1 = (const float*)d_in[3];
    const float* g1    = (const float*)d_in[4];
    const float* b1    = (const float*)d_in[5];
    const float* M2    = (const float*)d_in[6];
    const float* P2    = (const float*)d_in[7];
    const float* g2    = (const float*)d_in[8];
    const float* b2    = (const float*)d_in[9];
    float* out = (float*)d_out;

    const size_t need = (size_t)2 * S_LEN * NE * sizeof(__half);   // 37.75 MB
    if (ws_size >= need) {
        __half* W1 = (__half*)d_ws;
        __half* W2 = W1 + (size_t)S_LEN * NE;
        w_kernel<<<dim3(NWBLK), dim3(NT_W), 0, stream>>>(P1, P2, W1, W2);
        consumer<<<dim3(S_LEN), dim3(NT_C), 0, stream>>>(
            seq, M1, Wres1, M2, g1, b1, g2, b2, W1, W2, out);
    } else {
        hier_fallback<<<dim3(S_LEN), dim3(NT_W), 0, stream>>>(
            seq, M1, P1, Wres1, g1, b1, M2, P2, g2, b2, out);
    }
}